// Round 8
// baseline (212.741 us; speedup 1.0000x reference)
//
#include <hip/hip_runtime.h>

#define VV 9
#define CC 24
#define HFF 120
#define WFF 160
#define HW (HFF*WFF)
#define NPAIR 45
#define SIMDIM 72
#define CPL 6      // channels per lane (quad scheme)
#define NBKT 1728  // 12x12x12 spatial buckets (8^3 voxel cells)
#define NBKT_PAD 2048

typedef _Float16 half2_t __attribute__((ext_vector_type(2)));
typedef __fp16 fp16x2_t __attribute__((ext_vector_type(2)));

__device__ __host__ __forceinline__ constexpr int triidx(int a, int b) {
  return a * VV - a * (a - 1) / 2 + (b - a);
}

__device__ __forceinline__ half2_t pack2(float a, float b) {
  return __builtin_bit_cast(half2_t, __builtin_amdgcn_cvt_pkrtz(a, b));
}

__device__ __forceinline__ float dot2acc(half2_t a, half2_t b, float c) {
#if __has_builtin(__builtin_amdgcn_fdot2)
  return __builtin_amdgcn_fdot2(a, b, c, false);
#else
  return c + (float)a[0] * (float)b[0] + (float)a[1] * (float)b[1];
#endif
}

__device__ __forceinline__ int bucket_key(int x, int y, int z) {
  int kx = min(max(x, 0) >> 3, 11);
  int ky = min(max(y, 0) >> 3, 11);
  int kz = min(max(z, 0) >> 3, 11);
  return (kx * 12 + ky) * 12 + kz;
}

// ---------------- bucketing pipeline ----------------
__global__ __launch_bounds__(256)
void k_hist(const int* __restrict__ coords, int* __restrict__ hist, int n) {
  int i = blockIdx.x * 256 + threadIdx.x;
  if (i >= n) return;
  int key = bucket_key(coords[i * 4 + 1], coords[i * 4 + 2], coords[i * 4 + 3]);
  atomicAdd(&hist[key], 1);
}

// exclusive scan over NBKT_PAD entries, single block of 256, 8 per thread
__global__ __launch_bounds__(256)
void k_scan(const int* __restrict__ hist, int* __restrict__ offs) {
  __shared__ int sh[256];
  int t = threadIdx.x;
  int loc[8];
  int s = 0;
#pragma unroll
  for (int j = 0; j < 8; ++j) loc[j] = hist[t * 8 + j];
#pragma unroll
  for (int j = 0; j < 8; ++j) { int v = loc[j]; loc[j] = s; s += v; }
  sh[t] = s;
  __syncthreads();
  for (int off = 1; off < 256; off <<= 1) {
    int v = (t >= off) ? sh[t - off] : 0;
    __syncthreads();
    sh[t] += v;
    __syncthreads();
  }
  int base = sh[t] - s;  // exclusive
#pragma unroll
  for (int j = 0; j < 8; ++j) offs[t * 8 + j] = base + loc[j];
}

// scatter voxels into bucket-sorted order; store (x,y,z,origIdx)
__global__ __launch_bounds__(256)
void k_scatter(const int* __restrict__ coords, const int* __restrict__ offs,
               int* __restrict__ cnt, int4* __restrict__ cvox, int n) {
  int i = blockIdx.x * 256 + threadIdx.x;
  if (i >= n) return;
  int x = coords[i * 4 + 1], y = coords[i * 4 + 2], z = coords[i * 4 + 3];
  int key = bucket_key(x, y, z);
  int rank = atomicAdd(&cnt[key], 1);
  cvox[offs[key] + rank] = make_int4(x, y, z, i);
}

// (V,C,H,W) -> (V,H,W,C)
__global__ __launch_bounds__(256)
void vf_transpose(const float* __restrict__ feats, float* __restrict__ tf, int total) {
  int i = blockIdx.x * 256 + threadIdx.x;
  if (i >= total) return;
  int v = i / HW;
  int hw = i - v * HW;
  const float* s = feats + (size_t)v * CC * HW + hw;
  float4* d = (float4*)(tf + (size_t)i * CC);
#pragma unroll
  for (int c4 = 0; c4 < CC / 4; ++c4) {
    float4 o;
    o.x = s[(size_t)(c4 * 4 + 0) * HW];
    o.y = s[(size_t)(c4 * 4 + 1) * HW];
    o.z = s[(size_t)(c4 * 4 + 2) * HW];
    o.w = s[(size_t)(c4 * 4 + 3) * HW];
    d[c4] = o;
  }
}

// ---------------- main: 4 lanes/voxel, bucket-sorted, XCD-chunked ----------------
// Plain __launch_bounds__(256): a min-waves clamp spills to scratch (R4 lesson).
// R7: f stored as 27 packed half2 (was 54 f32), gram via v_dot2_f32_f16, mask as
// bitmask int, per-block z-partials fused in (k_zpart pass removed). Target VGPR<=128
// for 4 waves/SIMD (R6: 156 -> 3 waves, latency-bound at 124us).
__global__ __launch_bounds__(256)
void vf_main4p(const int4* __restrict__ cvox,
               const float* __restrict__ tfeats,
               const float* __restrict__ proj_feat,
               const float* __restrict__ proj_img,
               const float* __restrict__ origin,
               const float* __restrict__ W_vs,
               const float* __restrict__ b_vs,
               const float* __restrict__ voxel_size,
               const int* __restrict__ scale,
               const int* __restrict__ im_h_p,
               const int* __restrict__ im_w_p,
               float* __restrict__ out,
               double* __restrict__ partials,
               int n) {
  __shared__ float sPF[VV * 12], sPI[VV * 12], sWT[VV * SIMDIM], sB[VV];
  __shared__ double sRed[3][4];

  int tid = threadIdx.x;
  for (int t = tid; t < VV * 12; t += 256) {
    int v = t / 12, r = t - v * 12;
    sPF[t] = proj_feat[v * 16 + r];
    sPI[t] = proj_img[v * 16 + r];
  }
  // W_vs is [72][9]; store transposed sWT[j][k] for per-lane column access
  for (int t = tid; t < SIMDIM * VV; t += 256) {
    int k = t / 9, j = t - k * 9;
    sWT[j * SIMDIM + k] = W_vs[t];
  }
  if (tid < VV) sB[tid] = b_vs[tid];
  __syncthreads();

  // bijective XCD-chunked swizzle: consecutive data chunks -> one XCD
  int nb = gridDim.x;
  int q = nb >> 3, r8 = nb & 7;
  int xcd = blockIdx.x & 7, idx = blockIdx.x >> 3;
  int sb = (xcd < r8 ? xcd * (q + 1) : r8 * (q + 1) + (xcd - r8) * q) + idx;

  int lr = tid & 3;       // lane-in-quad: channels [6*lr, 6*lr+6), corners {2*lr, 2*lr+1}
  int vq = tid >> 2;      // local voxel 0..63
  int slot = sb * 64 + vq;
  bool active = slot < n;

  half2_t f[VV][CPL / 2];   // packed fp16 features (27 VGPRs, was 54)
  int mkbits = 0;           // visibility bitmask, bit v
  float msum = 0.f, zmean = 0.f;
  int i0 = 0;

  if (active) {
    int4 pc = cvox[slot];
    i0 = pc.w;
    float vs = voxel_size[0];
    float half = ldexpf(0.5f * vs, scale[0]);
    float wxp = (float)pc.x * vs + origin[0];
    float wyp = (float)pc.y * vs + origin[1];
    float wzp = (float)pc.z * vs + origin[2];
    float imw1 = (float)(im_w_p[0] - 1), imh1 = (float)(im_h_p[0] - 1);
    float cx2 = 2.f / imw1;     // |2(X/Z)/imw1 - 1| <= 1.1  <=>  |X*cx2 - Z| <= 1.1*Z  (Z>0)
    float cy2 = 2.f / imh1;
    // this lane's two corners: s0 = +/-1; s1,s2 from lr bits
    float s1 = (lr & 1) ? -1.f : 1.f;
    float s2 = (lr & 2) ? -1.f : 1.f;
    float zsum = 0.f;

#pragma unroll
    for (int v = 0; v < VV; ++v) {
      const float* M = &sPF[v * 12];
      float px = M[0] * wxp + M[1] * wyp + M[2] * wzp + M[3];
      float py = M[4] * wxp + M[5] * wyp + M[6] * wzp + M[7];
      float pz = M[8] * wxp + M[9] * wyp + M[10] * wzp + M[11];
      const float* P = &sPI[v * 12];
      float qx = P[0] * wxp + P[1] * wyp + P[2] * wzp + P[3];
      float qy = P[4] * wxp + P[5] * wyp + P[6] * wzp + P[7];
      float qz = P[8] * wxp + P[9] * wyp + P[10] * wzp + P[11];
      float h0x = P[0] * half, h1x = P[1] * half, h2x = P[2] * half;
      float h0y = P[4] * half, h1y = P[5] * half, h2y = P[6] * half;
      float h0z = P[8] * half, h1z = P[9] * half, h2z = P[10] * half;

      // two corners per lane (divide-free test), OR over quad
      float Xc = qx + s1 * h1x + s2 * h2x;
      float Yc = qy + s1 * h1y + s2 * h2y;
      float Zc = qz + s1 * h1z + s2 * h2z;
      int mbit = 0;
      {
        float X = Xc + h0x, Y = Yc + h0y, Z = Zc + h0z;
        if (Z > 0.f && fabsf(X * cx2 - Z) <= 1.1f * Z && fabsf(Y * cy2 - Z) <= 1.1f * Z) mbit = 1;
      }
      {
        float X = Xc - h0x, Y = Yc - h0y, Z = Zc - h0z;
        if (Z > 0.f && fabsf(X * cx2 - Z) <= 1.1f * Z && fabsf(Y * cy2 - Z) <= 1.1f * Z) mbit = 1;
      }
      mbit |= __shfl_xor(mbit, 1);
      mbit |= __shfl_xor(mbit, 2);
      float mkv = mbit ? 1.f : 0.f;
      mkbits |= mbit << v;
      zsum += pz * mkv;
      msum += mkv;

      float rpz = 1.f / pz;
      float x = fminf(fmaxf(px * rpz, 0.f), (float)(WFF - 1));
      float y = fminf(fmaxf(py * rpz, 0.f), (float)(HFF - 1));
      float x0f = floorf(x), y0f = floorf(y);
      float fxv = x - x0f, fyv = y - y0f;
      int x0 = (int)x0f, y0 = (int)y0f;
      x0 = min(max(x0, 0), WFF - 1);
      y0 = min(max(y0, 0), HFF - 1);
      int x1 = min(x0 + 1, WFF - 1), y1 = min(y0 + 1, HFF - 1);
      int base = ((v * HFF + y0) * WFF + x0) * CC + CPL * lr;
      int dxo = (x1 - x0) * CC;
      int dyo = (y1 - y0) * WFF * CC;
      float w00 = (1.f - fxv) * (1.f - fyv) * mkv;
      float w01 = fxv * (1.f - fyv) * mkv;
      float w10 = (1.f - fxv) * fyv * mkv;
      float w11 = fxv * fyv * mkv;

      const float* bp = tfeats + base;
#pragma unroll
      for (int j = 0; j < CPL / 2; ++j) {
        float2 a = *(const float2*)(bp + 2 * j);
        float2 b = *(const float2*)(bp + dxo + 2 * j);
        float2 c = *(const float2*)(bp + dyo + 2 * j);
        float2 d = *(const float2*)(bp + dxo + dyo + 2 * j);
        float e0 = w00 * a.x + w01 * b.x + w10 * c.x + w11 * d.x;
        float e1 = w00 * a.y + w01 * b.y + w10 * c.y + w11 * d.y;
        f[v][j] = pack2(e0, e1);
      }
    }
    zmean = zsum / (msum + 1e-10f);
  } else {
#pragma unroll
    for (int v = 0; v < VV; ++v)
#pragma unroll
      for (int j = 0; j < CPL / 2; ++j) f[v][j] = half2_t{0, 0};
  }

  // ---- partial gram over this lane's 6 channels (fp16 dot2, fp32 accum) ----
  float gram[NPAIR];
  {
    int p = 0;
#pragma unroll
    for (int v = 0; v < VV; ++v)
#pragma unroll
      for (int w = v; w < VV; ++w, ++p) {
        float s = 0.f;
#pragma unroll
        for (int j = 0; j < CPL / 2; ++j) s = dot2acc(f[v][j], f[w][j], s);
        gram[p] = s;
      }
  }
#pragma unroll
  for (int p = 0; p < NPAIR; ++p) {
    gram[p] += __shfl_xor(gram[p], 1);
    gram[p] += __shfl_xor(gram[p], 2);
  }

  if (active) {
    float inv[VV];
#pragma unroll
    for (int v = 0; v < VV; ++v) inv[v] = 1.f / (sqrtf(gram[triidx(v, v)]) + 1e-10f);

    // logit columns split across quad: lane lr owns cols {2lr, 2lr+1}; col 8 on all lanes
    float l0 = 0.f, l1 = 0.f, l2 = 0.f;
    const float* w0 = &sWT[(2 * lr) * SIMDIM];
    const float* w1 = &sWT[(2 * lr + 1) * SIMDIM];
    const float* w8 = &sWT[8 * SIMDIM];
    int k = 0;
#pragma unroll
    for (int v = 0; v < VV; ++v) {
#pragma unroll
      for (int w = 0; w < VV; ++w) {
        if (w == v) continue;
        int a = v < w ? v : w, b2 = v < w ? w : v;
        float s = gram[triidx(a, b2)] * inv[v] * inv[w];
        l0 += s * w0[k];
        l1 += s * w1[k];
        l2 += s * w8[k];
        ++k;
      }
    }
    int qb = (tid & 63) & ~3;
    float logit[VV];
    logit[0] = __shfl(l0, qb + 0); logit[1] = __shfl(l1, qb + 0);
    logit[2] = __shfl(l0, qb + 1); logit[3] = __shfl(l1, qb + 1);
    logit[4] = __shfl(l0, qb + 2); logit[5] = __shfl(l1, qb + 2);
    logit[6] = __shfl(l0, qb + 3); logit[7] = __shfl(l1, qb + 3);
    logit[8] = l2;
#pragma unroll
    for (int j = 0; j < VV; ++j) logit[j] += sB[j];

    float mx = logit[0];
#pragma unroll
    for (int j = 1; j < VV; ++j) mx = fmaxf(mx, logit[j]);
    float wt[VV], se = 0.f;
#pragma unroll
    for (int j = 0; j < VV; ++j) {
      wt[j] = __expf(logit[j] - mx);
      se += wt[j];
    }
    float rse = 1.f / se;
#pragma unroll
    for (int j = 0; j < VV; ++j) wt[j] = ((mkbits >> j) & 1) ? wt[j] * rse : 0.f;

    // fused features: straight from registers to the voxel's output row
    float* fvrow = out + (size_t)i0 * 25 + CPL * lr;
#pragma unroll
    for (int j = 0; j < CPL / 2; ++j) {
      float a0 = 0.f, a1 = 0.f;
#pragma unroll
      for (int v = 0; v < VV; ++v) {
        a0 += wt[v] * (float)f[v][j][0];
        a1 += wt[v] * (float)f[v][j][1];
      }
      fvrow[2 * j + 0] = a0;
      fvrow[2 * j + 1] = a1;
    }
    if (lr == 3) out[(size_t)i0 * 25 + CC] = zmean;  // stash zmean; znorm rewrites
    float* vwrow = out + (size_t)n * 25 + (size_t)i0 * 9;
    vwrow[lr] = wt[lr];
    vwrow[lr + 4] = wt[lr + 4];
    if (lr == 0) vwrow[8] = wt[8];
    if (lr == 1) out[(size_t)n * 34 + i0] = msum;
  }

  // ---- fused per-block z statistics (one contribution per voxel, lr==0) ----
  float zm = (active && lr == 0) ? zmean : 0.f;
  bool pos = zm > 0.f;
  double s = pos ? (double)zm : 0.0;
  double ss = pos ? (double)zm * (double)zm : 0.0;
  double cn = pos ? 1.0 : 0.0;
#pragma unroll
  for (int off = 32; off > 0; off >>= 1) {
    s += __shfl_down(s, off);
    ss += __shfl_down(ss, off);
    cn += __shfl_down(cn, off);
  }
  int wid = tid >> 6, lane = tid & 63;
  if (lane == 0) { sRed[0][wid] = s; sRed[1][wid] = ss; sRed[2][wid] = cn; }
  __syncthreads();
  if (tid == 0) {
    double S = 0, SS = 0, CN = 0;
    for (int w2 = 0; w2 < 4; ++w2) { S += sRed[0][w2]; SS += sRed[1][w2]; CN += sRed[2][w2]; }
    partials[blockIdx.x * 3 + 0] = S;
    partials[blockIdx.x * 3 + 1] = SS;
    partials[blockIdx.x * 3 + 2] = CN;
  }
}

// ---- z statistics from the stashed zmean column (tier-B only) ----
__global__ __launch_bounds__(256)
void k_zpart(const float* __restrict__ out, double* __restrict__ partials, int n) {
  __shared__ double sRed[3][4];
  int i = blockIdx.x * 256 + threadIdx.x;
  float zm = (i < n) ? out[(size_t)i * 25 + CC] : 0.f;
  bool pos = zm > 0.f;
  double s = pos ? (double)zm : 0.0;
  double ss = pos ? (double)zm * (double)zm : 0.0;
  double cn = pos ? 1.0 : 0.0;
#pragma unroll
  for (int off = 32; off > 0; off >>= 1) {
    s += __shfl_down(s, off);
    ss += __shfl_down(ss, off);
    cn += __shfl_down(cn, off);
  }
  int wid = threadIdx.x >> 6, lane = threadIdx.x & 63;
  if (lane == 0) { sRed[0][wid] = s; sRed[1][wid] = ss; sRed[2][wid] = cn; }
  __syncthreads();
  if (threadIdx.x == 0) {
    double S = 0, SS = 0, CN = 0;
    for (int w2 = 0; w2 < 4; ++w2) { S += sRed[0][w2]; SS += sRed[1][w2]; CN += sRed[2][w2]; }
    partials[blockIdx.x * 3 + 0] = S;
    partials[blockIdx.x * 3 + 1] = SS;
    partials[blockIdx.x * 3 + 2] = CN;
  }
}

__global__ __launch_bounds__(256)
void vf_reduce(const double* __restrict__ partials, int nb, float* __restrict__ musd) {
  __shared__ double sh[3][4];
  double s = 0, ss = 0, cn = 0;
  for (int b = threadIdx.x; b < nb; b += 256) {
    s += partials[b * 3 + 0];
    ss += partials[b * 3 + 1];
    cn += partials[b * 3 + 2];
  }
#pragma unroll
  for (int off = 32; off > 0; off >>= 1) {
    s += __shfl_down(s, off);
    ss += __shfl_down(ss, off);
    cn += __shfl_down(cn, off);
  }
  int wid = threadIdx.x >> 6, lane = threadIdx.x & 63;
  if (lane == 0) { sh[0][wid] = s; sh[1][wid] = ss; sh[2][wid] = cn; }
  __syncthreads();
  if (threadIdx.x == 0) {
    double S = 0, SS = 0, CN = 0;
    for (int w2 = 0; w2 < 4; ++w2) { S += sh[0][w2]; SS += sh[1][w2]; CN += sh[2][w2]; }
    double cnt = CN < 1.0 ? 1.0 : CN;
    double mu = S / cnt;
    double ssd = SS - 2.0 * mu * S + mu * mu * CN;
    if (ssd < 0.0) ssd = 0.0;
    double sd = sqrt(ssd) + 1e-5;
    musd[0] = (float)mu;
    musd[1] = (float)sd;
  }
}

__global__ __launch_bounds__(256)
void vf_znorm(float* __restrict__ out, const float* __restrict__ musd, int n) {
  int i = blockIdx.x * 256 + threadIdx.x;
  if (i >= n) return;
  float z = out[(size_t)i * 25 + CC];
  float mu = musd[0], sd = musd[1];
  out[(size_t)i * 25 + CC] = (z > 0.f) ? (z - mu) / sd : 0.f;
}

// ---------------- tier-B main (no permutation, LDS-staged output; fp32 path) ----------------
__global__ __launch_bounds__(256)
void vf_main4(const int* __restrict__ coords,
              const float* __restrict__ tfeats,
              const float* __restrict__ proj_feat,
              const float* __restrict__ proj_img,
              const float* __restrict__ origin,
              const float* __restrict__ W_vs,
              const float* __restrict__ b_vs,
              const float* __restrict__ voxel_size,
              const int* __restrict__ scale,
              const int* __restrict__ im_h_p,
              const int* __restrict__ im_w_p,
              float* __restrict__ out,
              int n) {
  __shared__ float sPF[VV * 12], sPI[VV * 12], sW[SIMDIM * VV], sB[VV];
  __shared__ float4 sFV4[64 * 25 / 4 + 1];
  __shared__ float4 sVW4[64 * 9 / 4];
  __shared__ float sCNT[64];
  float* sFV = (float*)sFV4;
  float* sVW = (float*)sVW4;

  int tid = threadIdx.x;
  for (int t = tid; t < VV * 12; t += 256) {
    int v = t / 12, r = t - v * 12;
    sPF[t] = proj_feat[v * 16 + r];
    sPI[t] = proj_img[v * 16 + r];
  }
  for (int t = tid; t < SIMDIM * VV; t += 256) sW[t] = W_vs[t];
  if (tid < VV) sB[tid] = b_vs[tid];
  __syncthreads();

  int lr = tid & 3;
  int vloc = tid >> 2;
  int vox = blockIdx.x * 64 + vloc;
  bool active = vox < n;
  float zmean = 0.f;

  float f[VV][CPL];
  float mk[VV];
  float msum = 0.f;

  if (active) {
    float vs = voxel_size[0];
    float half = ldexpf(0.5f * vs, scale[0]);
    float wxp = (float)coords[vox * 4 + 1] * vs + origin[0];
    float wyp = (float)coords[vox * 4 + 2] * vs + origin[1];
    float wzp = (float)coords[vox * 4 + 3] * vs + origin[2];
    float imw1 = (float)(im_w_p[0] - 1), imh1 = (float)(im_h_p[0] - 1);
    float zsum = 0.f;

#pragma unroll
    for (int v = 0; v < VV; ++v) {
      const float* M = &sPF[v * 12];
      float px = M[0] * wxp + M[1] * wyp + M[2] * wzp + M[3];
      float py = M[4] * wxp + M[5] * wyp + M[6] * wzp + M[7];
      float pz = M[8] * wxp + M[9] * wyp + M[10] * wzp + M[11];
      const float* P = &sPI[v * 12];
      float qx = P[0] * wxp + P[1] * wyp + P[2] * wzp + P[3];
      float qy = P[4] * wxp + P[5] * wyp + P[6] * wzp + P[7];
      float qz = P[8] * wxp + P[9] * wyp + P[10] * wzp + P[11];
      float h0x = P[0] * half, h1x = P[1] * half, h2x = P[2] * half;
      float h0y = P[4] * half, h1y = P[5] * half, h2y = P[6] * half;
      float h0z = P[8] * half, h1z = P[9] * half, h2z = P[10] * half;
      bool m = false;
#pragma unroll
      for (int k = 0; k < 8; ++k) {
        float s0 = (k & 1) ? -1.f : 1.f;
        float s1 = (k & 2) ? -1.f : 1.f;
        float s2 = (k & 4) ? -1.f : 1.f;
        float X = qx + s0 * h0x + s1 * h1x + s2 * h2x;
        float Y = qy + s0 * h0y + s1 * h1y + s2 * h2y;
        float Z = qz + s0 * h0z + s1 * h1z + s2 * h2z;
        float gxc = 2.f * (X / Z) / imw1 - 1.f;
        float gyc = 2.f * (Y / Z) / imh1 - 1.f;
        m = m || (fabsf(gxc) <= 1.1f && fabsf(gyc) <= 1.1f && Z > 0.f);
      }
      float mkv = m ? 1.f : 0.f;
      mk[v] = mkv;
      zsum += pz * mkv;
      msum += mkv;

      float x = fminf(fmaxf(px / pz, 0.f), (float)(WFF - 1));
      float y = fminf(fmaxf(py / pz, 0.f), (float)(HFF - 1));
      float x0f = floorf(x), y0f = floorf(y);
      float fxv = x - x0f, fyv = y - y0f;
      int x0 = (int)x0f, y0 = (int)y0f;
      x0 = min(max(x0, 0), WFF - 1);
      y0 = min(max(y0, 0), HFF - 1);
      int x1 = min(x0 + 1, WFF - 1), y1 = min(y0 + 1, HFF - 1);
      int base = ((v * HFF + y0) * WFF + x0) * CC + CPL * lr;
      int dxo = (x1 - x0) * CC;
      int dyo = (y1 - y0) * WFF * CC;
      float w00 = (1.f - fxv) * (1.f - fyv) * mkv;
      float w01 = fxv * (1.f - fyv) * mkv;
      float w10 = (1.f - fxv) * fyv * mkv;
      float w11 = fxv * fyv * mkv;

      const float* bp = tfeats + base;
#pragma unroll
      for (int j = 0; j < CPL / 2; ++j) {
        float2 a = *(const float2*)(bp + 2 * j);
        float2 b = *(const float2*)(bp + dxo + 2 * j);
        float2 c = *(const float2*)(bp + dyo + 2 * j);
        float2 d = *(const float2*)(bp + dxo + dyo + 2 * j);
        f[v][2 * j + 0] = w00 * a.x + w01 * b.x + w10 * c.x + w11 * d.x;
        f[v][2 * j + 1] = w00 * a.y + w01 * b.y + w10 * c.y + w11 * d.y;
      }
    }
    zmean = zsum / (msum + 1e-10f);
  } else {
#pragma unroll
    for (int v = 0; v < VV; ++v) {
      mk[v] = 0.f;
#pragma unroll
      for (int c = 0; c < CPL; ++c) f[v][c] = 0.f;
    }
  }

  float gram[NPAIR];
  {
    int p = 0;
#pragma unroll
    for (int v = 0; v < VV; ++v)
#pragma unroll
      for (int w = v; w < VV; ++w, ++p) {
        float s = 0.f;
#pragma unroll
        for (int c = 0; c < CPL; ++c) s += f[v][c] * f[w][c];
        gram[p] = s;
      }
  }
#pragma unroll
  for (int p = 0; p < NPAIR; ++p) {
    gram[p] += __shfl_xor(gram[p], 1);
    gram[p] += __shfl_xor(gram[p], 2);
  }

  if (active) {
    float inv[VV];
#pragma unroll
    for (int v = 0; v < VV; ++v) inv[v] = 1.f / (sqrtf(gram[triidx(v, v)]) + 1e-10f);

    float logit[VV];
#pragma unroll
    for (int j = 0; j < VV; ++j) logit[j] = sB[j];
    int k = 0;
#pragma unroll
    for (int v = 0; v < VV; ++v) {
#pragma unroll
      for (int w = 0; w < VV; ++w) {
        if (w == v) continue;
        int a = v < w ? v : w, b2 = v < w ? w : v;
        float s = gram[triidx(a, b2)] * inv[v] * inv[w];
#pragma unroll
        for (int j = 0; j < VV; ++j) logit[j] += s * sW[k * VV + j];
        ++k;
      }
    }

    float mx = logit[0];
#pragma unroll
    for (int j = 1; j < VV; ++j) mx = fmaxf(mx, logit[j]);
    float wt[VV], se = 0.f;
#pragma unroll
    for (int j = 0; j < VV; ++j) {
      wt[j] = __expf(logit[j] - mx);
      se += wt[j];
    }
    float rse = 1.f / se;
#pragma unroll
    for (int j = 0; j < VV; ++j) wt[j] = wt[j] * rse * mk[j];

#pragma unroll
    for (int c = 0; c < CPL; ++c) {
      float acc = 0.f;
#pragma unroll
      for (int v = 0; v < VV; ++v) acc += wt[v] * f[v][c];
      sFV[vloc * 25 + CPL * lr + c] = acc;
    }
    if (lr == 0) {
      sFV[vloc * 25 + CC] = zmean;
#pragma unroll
      for (int j = 0; j < VV; ++j) sVW[vloc * 9 + j] = wt[j];
      sCNT[vloc] = msum;
    }
  }
  __syncthreads();

  int vb = blockIdx.x * 64;
  int cv = min(64, n - vb);
  if (cv == 64) {
    float4* dfv = (float4*)(out + (size_t)vb * 25);
    for (int t = tid; t < 400; t += 256) dfv[t] = sFV4[t];
    float4* dvw = (float4*)(out + (size_t)n * 25 + (size_t)vb * 9);
    for (int t = tid; t < 144; t += 256) dvw[t] = sVW4[t];
    if (tid < 64) out[(size_t)n * 34 + vb + tid] = sCNT[tid];
  } else if (cv > 0) {
    for (int t = tid; t < cv * 25; t += 256) out[(size_t)vb * 25 + t] = sFV[t];
    for (int t = tid; t < cv * 9; t += 256) out[(size_t)n * 25 + (size_t)vb * 9 + t] = sVW[t];
    if (tid < cv) out[(size_t)n * 34 + vb + tid] = sCNT[tid];
  }
}

extern "C" void kernel_launch(void* const* d_in, const int* in_sizes, int n_in,
                              void* d_out, int out_size, void* d_ws, size_t ws_size,
                              hipStream_t stream) {
  const int* coords = (const int*)d_in[0];
  const float* feats = (const float*)d_in[1];
  const float* proj_feat = (const float*)d_in[2];
  const float* proj_img = (const float*)d_in[3];
  const float* origin = (const float*)d_in[4];
  const float* W_vs = (const float*)d_in[5];
  const float* b_vs = (const float*)d_in[6];
  const float* voxel_size = (const float*)d_in[7];
  const int* scale = (const int*)d_in[8];
  const int* im_h = (const int*)d_in[9];
  const int* im_w = (const int*)d_in[10];

  int n = in_sizes[0] / 4;
  int nbq = (n + 63) / 64;       // main blocks (64 voxels each)
  int nbz = (n + 255) / 256;     // per-voxel grids
  int nbp = nbq > nbz ? nbq : nbz;  // partials sizing

  // workspace layout
  size_t off = 0;
  float* musd = (float*)d_ws;                     off += 256;
  int* hist = (int*)((char*)d_ws + off);          off += NBKT_PAD * 4;
  int* offs = (int*)((char*)d_ws + off);          off += NBKT_PAD * 4;
  int* cnt  = (int*)((char*)d_ws + off);          off += NBKT_PAD * 4;
  off = (off + 255) & ~(size_t)255;
  double* partials = (double*)((char*)d_ws + off); off += (size_t)nbp * 3 * 8;
  off = (off + 255) & ~(size_t)255;
  int4* cvox = (int4*)((char*)d_ws + off);        size_t cvox_off = off; off += (size_t)n * 16;
  off = (off + 255) & ~(size_t)255;
  float* tfeats = (float*)((char*)d_ws + off);
  size_t tf_bytes = (size_t)VV * HW * CC * 4;
  size_t need_full = off + tf_bytes;

  if (ws_size >= need_full) {
    // ---- tier A: bucket-sorted, XCD-chunked, fused z-partials ----
    // zero hist+offs+cnt (contiguous; d_ws is poisoned 0xAA — dirty cnt caused R3's OOB crash)
    (void)hipMemsetAsync(hist, 0, (size_t)NBKT_PAD * 3 * 4, stream);
    k_hist<<<dim3(nbz), dim3(256), 0, stream>>>(coords, hist, n);
    k_scan<<<dim3(1), dim3(256), 0, stream>>>(hist, offs);
    k_scatter<<<dim3(nbz), dim3(256), 0, stream>>>(coords, offs, cnt, cvox, n);
    vf_transpose<<<dim3((VV * HW + 255) / 256), dim3(256), 0, stream>>>(feats, tfeats, VV * HW);
    vf_main4p<<<dim3(nbq), dim3(256), 0, stream>>>(
        cvox, tfeats, proj_feat, proj_img, origin, W_vs, b_vs, voxel_size,
        scale, im_h, im_w, (float*)d_out, partials, n);
    vf_reduce<<<dim3(1), dim3(256), 0, stream>>>(partials, nbq, musd);
  } else {
    // ---- tier B: no permutation ----
    float* tfb = (float*)((char*)d_ws + cvox_off);
    vf_transpose<<<dim3((VV * HW + 255) / 256), dim3(256), 0, stream>>>(feats, tfb, VV * HW);
    vf_main4<<<dim3(nbq), dim3(256), 0, stream>>>(
        coords, tfb, proj_feat, proj_img, origin, W_vs, b_vs, voxel_size,
        scale, im_h, im_w, (float*)d_out, n);
    k_zpart<<<dim3(nbz), dim3(256), 0, stream>>>((const float*)d_out, partials, n);
    vf_reduce<<<dim3(1), dim3(256), 0, stream>>>(partials, nbz, musd);
  }
  vf_znorm<<<dim3(nbz), dim3(256), 0, stream>>>((float*)d_out, musd, n);
}

// Round 9
// 161.401 us; speedup vs baseline: 1.3181x; 1.3181x over previous
//
#include <hip/hip_runtime.h>

#define VV 9
#define CC 24
#define HFF 120
#define WFF 160
#define HW (HFF*WFF)
#define NPAIR 45
#define SIMDIM 72
#define CPL 6      // channels per lane (quad scheme)
#define NBKT 1728  // 12x12x12 spatial buckets (8^3 voxel cells)
#define NBKT_PAD 2048

typedef _Float16 half2_t __attribute__((ext_vector_type(2)));

__device__ __host__ __forceinline__ constexpr int triidx(int a, int b) {
  return a * VV - a * (a - 1) / 2 + (b - a);
}

__device__ __forceinline__ half2_t pack2(float a, float b) {
  return __builtin_bit_cast(half2_t, __builtin_amdgcn_cvt_pkrtz(a, b));
}

__device__ __forceinline__ float dot2acc(half2_t a, half2_t b, float c) {
#if __has_builtin(__builtin_amdgcn_fdot2)
  return __builtin_amdgcn_fdot2(a, b, c, false);
#else
  return c + (float)a[0] * (float)b[0] + (float)a[1] * (float)b[1];
#endif
}

__device__ __forceinline__ int bucket_key(int x, int y, int z) {
  int kx = min(max(x, 0) >> 3, 11);
  int ky = min(max(y, 0) >> 3, 11);
  int kz = min(max(z, 0) >> 3, 11);
  return (kx * 12 + ky) * 12 + kz;
}

// ---------------- fused: (V,C,H,W) f32 -> (V,H,W,C) f16 transpose + coord histogram ----------------
__global__ __launch_bounds__(256)
void k_t16_hist(const float* __restrict__ feats, half2_t* __restrict__ tf,
                const int* __restrict__ coords, int* __restrict__ hist,
                int n, int nbt) {
  int b = blockIdx.x;
  if (b < nbt) {
    int i = b * 256 + threadIdx.x;
    if (i >= VV * HW) return;
    int v = i / HW;
    int hw = i - v * HW;
    const float* s = feats + (size_t)v * CC * HW + hw;
    half2_t tmp[12];
#pragma unroll
    for (int c2 = 0; c2 < 12; ++c2)
      tmp[c2] = pack2(s[(size_t)(2 * c2) * HW], s[(size_t)(2 * c2 + 1) * HW]);
    uint4* d = (uint4*)(tf + (size_t)i * 12);   // 48 B/texel, 16B-aligned
    d[0] = *(uint4*)(tmp + 0);
    d[1] = *(uint4*)(tmp + 4);
    d[2] = *(uint4*)(tmp + 8);
  } else {
    int i = (b - nbt) * 256 + threadIdx.x;
    if (i >= n) return;
    int key = bucket_key(coords[i * 4 + 1], coords[i * 4 + 2], coords[i * 4 + 3]);
    atomicAdd(&hist[key], 1);
  }
}

// exclusive scan over NBKT_PAD entries, single block of 256, 8 per thread
__global__ __launch_bounds__(256)
void k_scan(const int* __restrict__ hist, int* __restrict__ offs) {
  __shared__ int sh[256];
  int t = threadIdx.x;
  int loc[8];
  int s = 0;
#pragma unroll
  for (int j = 0; j < 8; ++j) loc[j] = hist[t * 8 + j];
#pragma unroll
  for (int j = 0; j < 8; ++j) { int v = loc[j]; loc[j] = s; s += v; }
  sh[t] = s;
  __syncthreads();
  for (int off = 1; off < 256; off <<= 1) {
    int v = (t >= off) ? sh[t - off] : 0;
    __syncthreads();
    sh[t] += v;
    __syncthreads();
  }
  int base = sh[t] - s;  // exclusive
#pragma unroll
  for (int j = 0; j < 8; ++j) offs[t * 8 + j] = base + loc[j];
}

// scatter voxels into bucket-sorted order; store (x,y,z,origIdx)
__global__ __launch_bounds__(256)
void k_scatter(const int* __restrict__ coords, const int* __restrict__ offs,
               int* __restrict__ cnt, int4* __restrict__ cvox, int n) {
  int i = blockIdx.x * 256 + threadIdx.x;
  if (i >= n) return;
  int x = coords[i * 4 + 1], y = coords[i * 4 + 2], z = coords[i * 4 + 3];
  int key = bucket_key(x, y, z);
  int rank = atomicAdd(&cnt[key], 1);
  cvox[offs[key] + rank] = make_int4(x, y, z, i);
}

// (V,C,H,W) -> (V,H,W,C) fp32 (tier-B only)
__global__ __launch_bounds__(256)
void vf_transpose(const float* __restrict__ feats, float* __restrict__ tf, int total) {
  int i = blockIdx.x * 256 + threadIdx.x;
  if (i >= total) return;
  int v = i / HW;
  int hw = i - v * HW;
  const float* s = feats + (size_t)v * CC * HW + hw;
  float4* d = (float4*)(tf + (size_t)i * CC);
#pragma unroll
  for (int c4 = 0; c4 < CC / 4; ++c4) {
    float4 o;
    o.x = s[(size_t)(c4 * 4 + 0) * HW];
    o.y = s[(size_t)(c4 * 4 + 1) * HW];
    o.z = s[(size_t)(c4 * 4 + 2) * HW];
    o.w = s[(size_t)(c4 * 4 + 3) * HW];
    d[c4] = o;
  }
}

// ---------------- main: 4 lanes/voxel, bucket-sorted, XCD-chunked, fp16 feature map ----------------
// Plain __launch_bounds__(256): min-waves clamp spills to scratch (R4 lesson).
// R9: tfeats fp16 (8.3 MB footprint, L2-resident slabs), 3x4B loads/corner (halves
// in-flight load regs — the real VGPR consumer per R8 post-mortem), packed-fp16
// blend + fusion (v_pk_fma_f16).
__global__ __launch_bounds__(256)
void vf_main4p(const int4* __restrict__ cvox,
               const half2_t* __restrict__ tf,
               const float* __restrict__ proj_feat,
               const float* __restrict__ proj_img,
               const float* __restrict__ origin,
               const float* __restrict__ W_vs,
               const float* __restrict__ b_vs,
               const float* __restrict__ voxel_size,
               const int* __restrict__ scale,
               const int* __restrict__ im_h_p,
               const int* __restrict__ im_w_p,
               float* __restrict__ out,
               double* __restrict__ partials,
               int n) {
  __shared__ float sPF[VV * 12], sPI[VV * 12], sWT[VV * SIMDIM], sB[VV];
  __shared__ double sRed[3][4];

  int tid = threadIdx.x;
  for (int t = tid; t < VV * 12; t += 256) {
    int v = t / 12, r = t - v * 12;
    sPF[t] = proj_feat[v * 16 + r];
    sPI[t] = proj_img[v * 16 + r];
  }
  // W_vs is [72][9]; store transposed sWT[j][k] for per-lane column access
  for (int t = tid; t < SIMDIM * VV; t += 256) {
    int k = t / 9, j = t - k * 9;
    sWT[j * SIMDIM + k] = W_vs[t];
  }
  if (tid < VV) sB[tid] = b_vs[tid];
  __syncthreads();

  // bijective XCD-chunked swizzle: consecutive data chunks -> one XCD
  int nb = gridDim.x;
  int q = nb >> 3, r8 = nb & 7;
  int xcd = blockIdx.x & 7, idx = blockIdx.x >> 3;
  int sb = (xcd < r8 ? xcd * (q + 1) : r8 * (q + 1) + (xcd - r8) * q) + idx;

  int lr = tid & 3;       // lane-in-quad: channels [6*lr, 6*lr+6), corners {2*lr, 2*lr+1}
  int vq = tid >> 2;      // local voxel 0..63
  int slot = sb * 64 + vq;
  bool active = slot < n;

  half2_t f[VV][CPL / 2];   // packed fp16 features
  int mkbits = 0;           // visibility bitmask, bit v
  float msum = 0.f, zmean = 0.f;
  int i0 = 0;

  if (active) {
    int4 pc = cvox[slot];
    i0 = pc.w;
    float vs = voxel_size[0];
    float half = ldexpf(0.5f * vs, scale[0]);
    float wxp = (float)pc.x * vs + origin[0];
    float wyp = (float)pc.y * vs + origin[1];
    float wzp = (float)pc.z * vs + origin[2];
    float imw1 = (float)(im_w_p[0] - 1), imh1 = (float)(im_h_p[0] - 1);
    float cx2 = 2.f / imw1;     // |2(X/Z)/imw1 - 1| <= 1.1  <=>  |X*cx2 - Z| <= 1.1*Z  (Z>0)
    float cy2 = 2.f / imh1;
    float s1 = (lr & 1) ? -1.f : 1.f;
    float s2 = (lr & 2) ? -1.f : 1.f;
    float zsum = 0.f;

#pragma unroll
    for (int v = 0; v < VV; ++v) {
      const float* M = &sPF[v * 12];
      float px = M[0] * wxp + M[1] * wyp + M[2] * wzp + M[3];
      float py = M[4] * wxp + M[5] * wyp + M[6] * wzp + M[7];
      float pz = M[8] * wxp + M[9] * wyp + M[10] * wzp + M[11];
      const float* P = &sPI[v * 12];
      float qx = P[0] * wxp + P[1] * wyp + P[2] * wzp + P[3];
      float qy = P[4] * wxp + P[5] * wyp + P[6] * wzp + P[7];
      float qz = P[8] * wxp + P[9] * wyp + P[10] * wzp + P[11];
      float h0x = P[0] * half, h1x = P[1] * half, h2x = P[2] * half;
      float h0y = P[4] * half, h1y = P[5] * half, h2y = P[6] * half;
      float h0z = P[8] * half, h1z = P[9] * half, h2z = P[10] * half;

      // two corners per lane (divide-free test), OR over quad
      float Xc = qx + s1 * h1x + s2 * h2x;
      float Yc = qy + s1 * h1y + s2 * h2y;
      float Zc = qz + s1 * h1z + s2 * h2z;
      int mbit = 0;
      {
        float X = Xc + h0x, Y = Yc + h0y, Z = Zc + h0z;
        if (Z > 0.f && fabsf(X * cx2 - Z) <= 1.1f * Z && fabsf(Y * cy2 - Z) <= 1.1f * Z) mbit = 1;
      }
      {
        float X = Xc - h0x, Y = Yc - h0y, Z = Zc - h0z;
        if (Z > 0.f && fabsf(X * cx2 - Z) <= 1.1f * Z && fabsf(Y * cy2 - Z) <= 1.1f * Z) mbit = 1;
      }
      mbit |= __shfl_xor(mbit, 1);
      mbit |= __shfl_xor(mbit, 2);
      float mkv = mbit ? 1.f : 0.f;
      mkbits |= mbit << v;
      zsum += pz * mkv;
      msum += mkv;

      float rpz = 1.f / pz;
      float x = fminf(fmaxf(px * rpz, 0.f), (float)(WFF - 1));
      float y = fminf(fmaxf(py * rpz, 0.f), (float)(HFF - 1));
      float x0f = floorf(x), y0f = floorf(y);
      float fxv = x - x0f, fyv = y - y0f;
      int x0 = (int)x0f, y0 = (int)y0f;
      x0 = min(max(x0, 0), WFF - 1);
      y0 = min(max(y0, 0), HFF - 1);
      int x1 = min(x0 + 1, WFF - 1), y1 = min(y0 + 1, HFF - 1);
      // half2 units: texel stride 12
      int base2 = ((v * HFF + y0) * WFF + x0) * 12 + 3 * lr;
      int dx2 = (x1 - x0) * 12;
      int dy2 = (y1 - y0) * WFF * 12;
      float w00 = (1.f - fxv) * (1.f - fyv) * mkv;
      float w01 = fxv * (1.f - fyv) * mkv;
      float w10 = (1.f - fxv) * fyv * mkv;
      float w11 = fxv * fyv * mkv;
      half2_t W00 = pack2(w00, w00);
      half2_t W01 = pack2(w01, w01);
      half2_t W10 = pack2(w10, w10);
      half2_t W11 = pack2(w11, w11);

      const half2_t* bp = tf + base2;
#pragma unroll
      for (int j = 0; j < CPL / 2; ++j) {
        half2_t a = bp[j];
        half2_t b = bp[dx2 + j];
        half2_t c = bp[dy2 + j];
        half2_t d = bp[dx2 + dy2 + j];
        f[v][j] = a * W00 + b * W01 + c * W10 + d * W11;   // v_pk_fma_f16
      }
    }
    zmean = zsum / (msum + 1e-10f);
  } else {
#pragma unroll
    for (int v = 0; v < VV; ++v)
#pragma unroll
      for (int j = 0; j < CPL / 2; ++j) f[v][j] = half2_t{0, 0};
  }

  // ---- partial gram over this lane's 6 channels (fp16 dot2, fp32 accum) ----
  float gram[NPAIR];
  {
    int p = 0;
#pragma unroll
    for (int v = 0; v < VV; ++v)
#pragma unroll
      for (int w = v; w < VV; ++w, ++p) {
        float s = 0.f;
#pragma unroll
        for (int j = 0; j < CPL / 2; ++j) s = dot2acc(f[v][j], f[w][j], s);
        gram[p] = s;
      }
  }
#pragma unroll
  for (int p = 0; p < NPAIR; ++p) {
    gram[p] += __shfl_xor(gram[p], 1);
    gram[p] += __shfl_xor(gram[p], 2);
  }

  if (active) {
    float inv[VV];
#pragma unroll
    for (int v = 0; v < VV; ++v) inv[v] = 1.f / (sqrtf(gram[triidx(v, v)]) + 1e-10f);

    // logit columns split across quad: lane lr owns cols {2lr, 2lr+1}; col 8 on all lanes
    float l0 = 0.f, l1 = 0.f, l2 = 0.f;
    const float* w0 = &sWT[(2 * lr) * SIMDIM];
    const float* w1 = &sWT[(2 * lr + 1) * SIMDIM];
    const float* w8 = &sWT[8 * SIMDIM];
    int k = 0;
#pragma unroll
    for (int v = 0; v < VV; ++v) {
#pragma unroll
      for (int w = 0; w < VV; ++w) {
        if (w == v) continue;
        int a = v < w ? v : w, b2 = v < w ? w : v;
        float s = gram[triidx(a, b2)] * inv[v] * inv[w];
        l0 += s * w0[k];
        l1 += s * w1[k];
        l2 += s * w8[k];
        ++k;
      }
    }
    int qb = (tid & 63) & ~3;
    float logit[VV];
    logit[0] = __shfl(l0, qb + 0); logit[1] = __shfl(l1, qb + 0);
    logit[2] = __shfl(l0, qb + 1); logit[3] = __shfl(l1, qb + 1);
    logit[4] = __shfl(l0, qb + 2); logit[5] = __shfl(l1, qb + 2);
    logit[6] = __shfl(l0, qb + 3); logit[7] = __shfl(l1, qb + 3);
    logit[8] = l2;
#pragma unroll
    for (int j = 0; j < VV; ++j) logit[j] += sB[j];

    float mx = logit[0];
#pragma unroll
    for (int j = 1; j < VV; ++j) mx = fmaxf(mx, logit[j]);
    float wt[VV], se = 0.f;
#pragma unroll
    for (int j = 0; j < VV; ++j) {
      wt[j] = __expf(logit[j] - mx);
      se += wt[j];
    }
    float rse = 1.f / se;
#pragma unroll
    for (int j = 0; j < VV; ++j) wt[j] = ((mkbits >> j) & 1) ? wt[j] * rse : 0.f;

    // fused features: packed fp16 accumulate, fp32 store
    half2_t acc[CPL / 2];
#pragma unroll
    for (int j = 0; j < CPL / 2; ++j) acc[j] = half2_t{0, 0};
#pragma unroll
    for (int v = 0; v < VV; ++v) {
      half2_t wv = pack2(wt[v], wt[v]);
#pragma unroll
      for (int j = 0; j < CPL / 2; ++j) acc[j] += f[v][j] * wv;
    }
    float* fvrow = out + (size_t)i0 * 25 + CPL * lr;
#pragma unroll
    for (int j = 0; j < CPL / 2; ++j) {
      fvrow[2 * j + 0] = (float)acc[j][0];
      fvrow[2 * j + 1] = (float)acc[j][1];
    }
    if (lr == 3) out[(size_t)i0 * 25 + CC] = zmean;  // stash zmean; znorm rewrites
    float* vwrow = out + (size_t)n * 25 + (size_t)i0 * 9;
    vwrow[lr] = wt[lr];
    vwrow[lr + 4] = wt[lr + 4];
    if (lr == 0) vwrow[8] = wt[8];
    if (lr == 1) out[(size_t)n * 34 + i0] = msum;
  }

  // ---- fused per-block z statistics (one contribution per voxel, lr==0) ----
  float zm = (active && lr == 0) ? zmean : 0.f;
  bool pos = zm > 0.f;
  double s = pos ? (double)zm : 0.0;
  double ss = pos ? (double)zm * (double)zm : 0.0;
  double cn = pos ? 1.0 : 0.0;
#pragma unroll
  for (int off = 32; off > 0; off >>= 1) {
    s += __shfl_down(s, off);
    ss += __shfl_down(ss, off);
    cn += __shfl_down(cn, off);
  }
  int wid = tid >> 6, lane = tid & 63;
  if (lane == 0) { sRed[0][wid] = s; sRed[1][wid] = ss; sRed[2][wid] = cn; }
  __syncthreads();
  if (tid == 0) {
    double S = 0, SS = 0, CN = 0;
    for (int w2 = 0; w2 < 4; ++w2) { S += sRed[0][w2]; SS += sRed[1][w2]; CN += sRed[2][w2]; }
    partials[blockIdx.x * 3 + 0] = S;
    partials[blockIdx.x * 3 + 1] = SS;
    partials[blockIdx.x * 3 + 2] = CN;
  }
}

// ---- z statistics from the stashed zmean column (tier-B only) ----
__global__ __launch_bounds__(256)
void k_zpart(const float* __restrict__ out, double* __restrict__ partials, int n) {
  __shared__ double sRed[3][4];
  int i = blockIdx.x * 256 + threadIdx.x;
  float zm = (i < n) ? out[(size_t)i * 25 + CC] : 0.f;
  bool pos = zm > 0.f;
  double s = pos ? (double)zm : 0.0;
  double ss = pos ? (double)zm * (double)zm : 0.0;
  double cn = pos ? 1.0 : 0.0;
#pragma unroll
  for (int off = 32; off > 0; off >>= 1) {
    s += __shfl_down(s, off);
    ss += __shfl_down(ss, off);
    cn += __shfl_down(cn, off);
  }
  int wid = threadIdx.x >> 6, lane = threadIdx.x & 63;
  if (lane == 0) { sRed[0][wid] = s; sRed[1][wid] = ss; sRed[2][wid] = cn; }
  __syncthreads();
  if (threadIdx.x == 0) {
    double S = 0, SS = 0, CN = 0;
    for (int w2 = 0; w2 < 4; ++w2) { S += sRed[0][w2]; SS += sRed[1][w2]; CN += sRed[2][w2]; }
    partials[blockIdx.x * 3 + 0] = S;
    partials[blockIdx.x * 3 + 1] = SS;
    partials[blockIdx.x * 3 + 2] = CN;
  }
}

__global__ __launch_bounds__(256)
void vf_reduce(const double* __restrict__ partials, int nb, float* __restrict__ musd) {
  __shared__ double sh[3][4];
  double s = 0, ss = 0, cn = 0;
  for (int b = threadIdx.x; b < nb; b += 256) {
    s += partials[b * 3 + 0];
    ss += partials[b * 3 + 1];
    cn += partials[b * 3 + 2];
  }
#pragma unroll
  for (int off = 32; off > 0; off >>= 1) {
    s += __shfl_down(s, off);
    ss += __shfl_down(ss, off);
    cn += __shfl_down(cn, off);
  }
  int wid = threadIdx.x >> 6, lane = threadIdx.x & 63;
  if (lane == 0) { sh[0][wid] = s; sh[1][wid] = ss; sh[2][wid] = cn; }
  __syncthreads();
  if (threadIdx.x == 0) {
    double S = 0, SS = 0, CN = 0;
    for (int w2 = 0; w2 < 4; ++w2) { S += sh[0][w2]; SS += sh[1][w2]; CN += sh[2][w2]; }
    double cnt = CN < 1.0 ? 1.0 : CN;
    double mu = S / cnt;
    double ssd = SS - 2.0 * mu * S + mu * mu * CN;
    if (ssd < 0.0) ssd = 0.0;
    double sd = sqrt(ssd) + 1e-5;
    musd[0] = (float)mu;
    musd[1] = (float)sd;
  }
}

__global__ __launch_bounds__(256)
void vf_znorm(float* __restrict__ out, const float* __restrict__ musd, int n) {
  int i = blockIdx.x * 256 + threadIdx.x;
  if (i >= n) return;
  float z = out[(size_t)i * 25 + CC];
  float mu = musd[0], sd = musd[1];
  out[(size_t)i * 25 + CC] = (z > 0.f) ? (z - mu) / sd : 0.f;
}

// ---------------- tier-B main (no permutation, LDS-staged output; fp32 path) ----------------
__global__ __launch_bounds__(256)
void vf_main4(const int* __restrict__ coords,
              const float* __restrict__ tfeats,
              const float* __restrict__ proj_feat,
              const float* __restrict__ proj_img,
              const float* __restrict__ origin,
              const float* __restrict__ W_vs,
              const float* __restrict__ b_vs,
              const float* __restrict__ voxel_size,
              const int* __restrict__ scale,
              const int* __restrict__ im_h_p,
              const int* __restrict__ im_w_p,
              float* __restrict__ out,
              int n) {
  __shared__ float sPF[VV * 12], sPI[VV * 12], sW[SIMDIM * VV], sB[VV];
  __shared__ float4 sFV4[64 * 25 / 4 + 1];
  __shared__ float4 sVW4[64 * 9 / 4];
  __shared__ float sCNT[64];
  float* sFV = (float*)sFV4;
  float* sVW = (float*)sVW4;

  int tid = threadIdx.x;
  for (int t = tid; t < VV * 12; t += 256) {
    int v = t / 12, r = t - v * 12;
    sPF[t] = proj_feat[v * 16 + r];
    sPI[t] = proj_img[v * 16 + r];
  }
  for (int t = tid; t < SIMDIM * VV; t += 256) sW[t] = W_vs[t];
  if (tid < VV) sB[tid] = b_vs[tid];
  __syncthreads();

  int lr = tid & 3;
  int vloc = tid >> 2;
  int vox = blockIdx.x * 64 + vloc;
  bool active = vox < n;
  float zmean = 0.f;

  float f[VV][CPL];
  float mk[VV];
  float msum = 0.f;

  if (active) {
    float vs = voxel_size[0];
    float half = ldexpf(0.5f * vs, scale[0]);
    float wxp = (float)coords[vox * 4 + 1] * vs + origin[0];
    float wyp = (float)coords[vox * 4 + 2] * vs + origin[1];
    float wzp = (float)coords[vox * 4 + 3] * vs + origin[2];
    float imw1 = (float)(im_w_p[0] - 1), imh1 = (float)(im_h_p[0] - 1);
    float zsum = 0.f;

#pragma unroll
    for (int v = 0; v < VV; ++v) {
      const float* M = &sPF[v * 12];
      float px = M[0] * wxp + M[1] * wyp + M[2] * wzp + M[3];
      float py = M[4] * wxp + M[5] * wyp + M[6] * wzp + M[7];
      float pz = M[8] * wxp + M[9] * wyp + M[10] * wzp + M[11];
      const float* P = &sPI[v * 12];
      float qx = P[0] * wxp + P[1] * wyp + P[2] * wzp + P[3];
      float qy = P[4] * wxp + P[5] * wyp + P[6] * wzp + P[7];
      float qz = P[8] * wxp + P[9] * wyp + P[10] * wzp + P[11];
      float h0x = P[0] * half, h1x = P[1] * half, h2x = P[2] * half;
      float h0y = P[4] * half, h1y = P[5] * half, h2y = P[6] * half;
      float h0z = P[8] * half, h1z = P[9] * half, h2z = P[10] * half;
      bool m = false;
#pragma unroll
      for (int k = 0; k < 8; ++k) {
        float s0 = (k & 1) ? -1.f : 1.f;
        float s1 = (k & 2) ? -1.f : 1.f;
        float s2 = (k & 4) ? -1.f : 1.f;
        float X = qx + s0 * h0x + s1 * h1x + s2 * h2x;
        float Y = qy + s0 * h0y + s1 * h1y + s2 * h2y;
        float Z = qz + s0 * h0z + s1 * h1z + s2 * h2z;
        float gxc = 2.f * (X / Z) / imw1 - 1.f;
        float gyc = 2.f * (Y / Z) / imh1 - 1.f;
        m = m || (fabsf(gxc) <= 1.1f && fabsf(gyc) <= 1.1f && Z > 0.f);
      }
      float mkv = m ? 1.f : 0.f;
      mk[v] = mkv;
      zsum += pz * mkv;
      msum += mkv;

      float x = fminf(fmaxf(px / pz, 0.f), (float)(WFF - 1));
      float y = fminf(fmaxf(py / pz, 0.f), (float)(HFF - 1));
      float x0f = floorf(x), y0f = floorf(y);
      float fxv = x - x0f, fyv = y - y0f;
      int x0 = (int)x0f, y0 = (int)y0f;
      x0 = min(max(x0, 0), WFF - 1);
      y0 = min(max(y0, 0), HFF - 1);
      int x1 = min(x0 + 1, WFF - 1), y1 = min(y0 + 1, HFF - 1);
      int base = ((v * HFF + y0) * WFF + x0) * CC + CPL * lr;
      int dxo = (x1 - x0) * CC;
      int dyo = (y1 - y0) * WFF * CC;
      float w00 = (1.f - fxv) * (1.f - fyv) * mkv;
      float w01 = fxv * (1.f - fyv) * mkv;
      float w10 = (1.f - fxv) * fyv * mkv;
      float w11 = fxv * fyv * mkv;

      const float* bp = tfeats + base;
#pragma unroll
      for (int j = 0; j < CPL / 2; ++j) {
        float2 a = *(const float2*)(bp + 2 * j);
        float2 b = *(const float2*)(bp + dxo + 2 * j);
        float2 c = *(const float2*)(bp + dyo + 2 * j);
        float2 d = *(const float2*)(bp + dxo + dyo + 2 * j);
        f[v][2 * j + 0] = w00 * a.x + w01 * b.x + w10 * c.x + w11 * d.x;
        f[v][2 * j + 1] = w00 * a.y + w01 * b.y + w10 * c.y + w11 * d.y;
      }
    }
    zmean = zsum / (msum + 1e-10f);
  } else {
#pragma unroll
    for (int v = 0; v < VV; ++v) {
      mk[v] = 0.f;
#pragma unroll
      for (int c = 0; c < CPL; ++c) f[v][c] = 0.f;
    }
  }

  float gram[NPAIR];
  {
    int p = 0;
#pragma unroll
    for (int v = 0; v < VV; ++v)
#pragma unroll
      for (int w = v; w < VV; ++w, ++p) {
        float s = 0.f;
#pragma unroll
        for (int c = 0; c < CPL; ++c) s += f[v][c] * f[w][c];
        gram[p] = s;
      }
  }
#pragma unroll
  for (int p = 0; p < NPAIR; ++p) {
    gram[p] += __shfl_xor(gram[p], 1);
    gram[p] += __shfl_xor(gram[p], 2);
  }

  if (active) {
    float inv[VV];
#pragma unroll
    for (int v = 0; v < VV; ++v) inv[v] = 1.f / (sqrtf(gram[triidx(v, v)]) + 1e-10f);

    float logit[VV];
#pragma unroll
    for (int j = 0; j < VV; ++j) logit[j] = sB[j];
    int k = 0;
#pragma unroll
    for (int v = 0; v < VV; ++v) {
#pragma unroll
      for (int w = 0; w < VV; ++w) {
        if (w == v) continue;
        int a = v < w ? v : w, b2 = v < w ? w : v;
        float s = gram[triidx(a, b2)] * inv[v] * inv[w];
#pragma unroll
        for (int j = 0; j < VV; ++j) logit[j] += s * sW[k * VV + j];
        ++k;
      }
    }

    float mx = logit[0];
#pragma unroll
    for (int j = 1; j < VV; ++j) mx = fmaxf(mx, logit[j]);
    float wt[VV], se = 0.f;
#pragma unroll
    for (int j = 0; j < VV; ++j) {
      wt[j] = __expf(logit[j] - mx);
      se += wt[j];
    }
    float rse = 1.f / se;
#pragma unroll
    for (int j = 0; j < VV; ++j) wt[j] = wt[j] * rse * mk[j];

#pragma unroll
    for (int c = 0; c < CPL; ++c) {
      float acc = 0.f;
#pragma unroll
      for (int v = 0; v < VV; ++v) acc += wt[v] * f[v][c];
      sFV[vloc * 25 + CPL * lr + c] = acc;
    }
    if (lr == 0) {
      sFV[vloc * 25 + CC] = zmean;
#pragma unroll
      for (int j = 0; j < VV; ++j) sVW[vloc * 9 + j] = wt[j];
      sCNT[vloc] = msum;
    }
  }
  __syncthreads();

  int vb = blockIdx.x * 64;
  int cv = min(64, n - vb);
  if (cv == 64) {
    float4* dfv = (float4*)(out + (size_t)vb * 25);
    for (int t = tid; t < 400; t += 256) dfv[t] = sFV4[t];
    float4* dvw = (float4*)(out + (size_t)n * 25 + (size_t)vb * 9);
    for (int t = tid; t < 144; t += 256) dvw[t] = sVW4[t];
    if (tid < 64) out[(size_t)n * 34 + vb + tid] = sCNT[tid];
  } else if (cv > 0) {
    for (int t = tid; t < cv * 25; t += 256) out[(size_t)vb * 25 + t] = sFV[t];
    for (int t = tid; t < cv * 9; t += 256) out[(size_t)n * 25 + (size_t)vb * 9 + t] = sVW[t];
    if (tid < cv) out[(size_t)n * 34 + vb + tid] = sCNT[tid];
  }
}

extern "C" void kernel_launch(void* const* d_in, const int* in_sizes, int n_in,
                              void* d_out, int out_size, void* d_ws, size_t ws_size,
                              hipStream_t stream) {
  const int* coords = (const int*)d_in[0];
  const float* feats = (const float*)d_in[1];
  const float* proj_feat = (const float*)d_in[2];
  const float* proj_img = (const float*)d_in[3];
  const float* origin = (const float*)d_in[4];
  const float* W_vs = (const float*)d_in[5];
  const float* b_vs = (const float*)d_in[6];
  const float* voxel_size = (const float*)d_in[7];
  const int* scale = (const int*)d_in[8];
  const int* im_h = (const int*)d_in[9];
  const int* im_w = (const int*)d_in[10];

  int n = in_sizes[0] / 4;
  int nbq = (n + 63) / 64;       // main blocks (64 voxels each)
  int nbz = (n + 255) / 256;     // per-voxel grids
  int nbt = (VV * HW + 255) / 256;  // transpose blocks
  int nbp = nbq > nbz ? nbq : nbz;  // partials sizing

  // workspace layout
  size_t off = 0;
  float* musd = (float*)d_ws;                     off += 256;
  int* hist = (int*)((char*)d_ws + off);          off += NBKT_PAD * 4;
  int* offs = (int*)((char*)d_ws + off);          off += NBKT_PAD * 4;
  int* cnt  = (int*)((char*)d_ws + off);          off += NBKT_PAD * 4;
  off = (off + 255) & ~(size_t)255;
  double* partials = (double*)((char*)d_ws + off); off += (size_t)nbp * 3 * 8;
  off = (off + 255) & ~(size_t)255;
  int4* cvox = (int4*)((char*)d_ws + off);        size_t cvox_off = off; off += (size_t)n * 16;
  off = (off + 255) & ~(size_t)255;
  half2_t* tf16 = (half2_t*)((char*)d_ws + off);
  size_t tf16_bytes = (size_t)VV * HW * CC * 2;
  size_t need_full = off + tf16_bytes;
  size_t tf32_bytes = (size_t)VV * HW * CC * 4;

  if (ws_size >= need_full) {
    // ---- tier A: bucket-sorted, XCD-chunked, fp16 feature map, fused z-partials ----
    // zero hist+offs+cnt (contiguous; d_ws is poisoned 0xAA — dirty cnt caused R3's OOB crash)
    (void)hipMemsetAsync(hist, 0, (size_t)NBKT_PAD * 3 * 4, stream);
    k_t16_hist<<<dim3(nbt + nbz), dim3(256), 0, stream>>>(feats, tf16, coords, hist, n, nbt);
    k_scan<<<dim3(1), dim3(256), 0, stream>>>(hist, offs);
    k_scatter<<<dim3(nbz), dim3(256), 0, stream>>>(coords, offs, cnt, cvox, n);
    vf_main4p<<<dim3(nbq), dim3(256), 0, stream>>>(
        cvox, tf16, proj_feat, proj_img, origin, W_vs, b_vs, voxel_size,
        scale, im_h, im_w, (float*)d_out, partials, n);
    vf_reduce<<<dim3(1), dim3(256), 0, stream>>>(partials, nbq, musd);
  } else if (ws_size >= cvox_off + tf32_bytes) {
    // ---- tier B: no permutation, fp32 map ----
    float* tfb = (float*)((char*)d_ws + cvox_off);
    vf_transpose<<<dim3(nbt), dim3(256), 0, stream>>>(feats, tfb, VV * HW);
    vf_main4<<<dim3(nbq), dim3(256), 0, stream>>>(
        coords, tfb, proj_feat, proj_img, origin, W_vs, b_vs, voxel_size,
        scale, im_h, im_w, (float*)d_out, n);
    k_zpart<<<dim3(nbz), dim3(256), 0, stream>>>((const float*)d_out, partials, n);
    vf_reduce<<<dim3(1), dim3(256), 0, stream>>>(partials, nbz, musd);
  }
  vf_znorm<<<dim3(nbz), dim3(256), 0, stream>>>((float*)d_out, musd, n);
}

// Round 10
// 157.477 us; speedup vs baseline: 1.3509x; 1.0249x over previous
//
#include <hip/hip_runtime.h>

#define VV 9
#define CC 24
#define HFF 120
#define WFF 160
#define HW (HFF*WFF)
#define NPAIR 45
#define NOFF 36    // unordered off-diagonal pairs
#define SIMDIM 72
#define CPL 6      // channels per lane (quad scheme)
#define NBKT 1728  // 12x12x12 spatial buckets (8^3 voxel cells)
#define NBKT_PAD 2048

typedef _Float16 half2_t __attribute__((ext_vector_type(2)));
struct H2x4 { half2_t h[4]; };

__device__ __host__ __forceinline__ constexpr int triidx(int a, int b) {
  return a * VV - a * (a - 1) / 2 + (b - a);
}

__device__ __forceinline__ half2_t pack2(float a, float b) {
  return __builtin_bit_cast(half2_t, __builtin_amdgcn_cvt_pkrtz(a, b));
}

__device__ __forceinline__ float dot2acc(half2_t a, half2_t b, float c) {
#if __has_builtin(__builtin_amdgcn_fdot2)
  return __builtin_amdgcn_fdot2(a, b, c, false);
#else
  return c + (float)a[0] * (float)b[0] + (float)a[1] * (float)b[1];
#endif
}

__device__ __forceinline__ int bucket_key(int x, int y, int z) {
  int kx = min(max(x, 0) >> 3, 11);
  int ky = min(max(y, 0) >> 3, 11);
  int kz = min(max(z, 0) >> 3, 11);
  return (kx * 12 + ky) * 12 + kz;
}

// ---------------- fused: (V,C,H,W) f32 -> (V,H,W,C16pad) f16 transpose + coord histogram ----------------
// Texel = 64 B: 4 slots of 16 B (lane lr's 6 channels in first 12 B + 4 B pad) -> b128 gather loads.
__global__ __launch_bounds__(256)
void k_t16_hist(const float* __restrict__ feats, uint4* __restrict__ tf,
                const int* __restrict__ coords, int* __restrict__ hist,
                int n, int nbt) {
  int b = blockIdx.x;
  if (b < nbt) {
    int i = b * 256 + threadIdx.x;
    if (i >= VV * HW) return;
    int v = i / HW;
    int hw = i - v * HW;
    const float* s = feats + (size_t)v * CC * HW + hw;
    uint4* d = tf + (size_t)i * 4;
#pragma unroll
    for (int lr = 0; lr < 4; ++lr) {
      half2_t t0 = pack2(s[(size_t)(6 * lr + 0) * HW], s[(size_t)(6 * lr + 1) * HW]);
      half2_t t1 = pack2(s[(size_t)(6 * lr + 2) * HW], s[(size_t)(6 * lr + 3) * HW]);
      half2_t t2 = pack2(s[(size_t)(6 * lr + 4) * HW], s[(size_t)(6 * lr + 5) * HW]);
      H2x4 o;
      o.h[0] = t0; o.h[1] = t1; o.h[2] = t2; o.h[3] = half2_t{0, 0};
      d[lr] = __builtin_bit_cast(uint4, o);
    }
  } else {
    int i = (b - nbt) * 256 + threadIdx.x;
    if (i >= n) return;
    int key = bucket_key(coords[i * 4 + 1], coords[i * 4 + 2], coords[i * 4 + 3]);
    atomicAdd(&hist[key], 1);
  }
}

// exclusive scan over NBKT_PAD entries + zero cnt + precompute symmetrized W pairs
__global__ __launch_bounds__(256)
void k_scan(const int* __restrict__ hist, int* __restrict__ offs,
            int* __restrict__ cnt, const float* __restrict__ W_vs,
            float* __restrict__ wsym) {
  __shared__ int sh[256];
  int t = threadIdx.x;
  int loc[8];
  int s = 0;
#pragma unroll
  for (int j = 0; j < 8; ++j) loc[j] = hist[t * 8 + j];
#pragma unroll
  for (int j = 0; j < 8; ++j) { int v = loc[j]; loc[j] = s; s += v; }
  sh[t] = s;
  __syncthreads();
  for (int off = 1; off < 256; off <<= 1) {
    int v = (t >= off) ? sh[t - off] : 0;
    __syncthreads();
    sh[t] += v;
    __syncthreads();
  }
  int base = sh[t] - s;  // exclusive
#pragma unroll
  for (int j = 0; j < 8; ++j) {
    offs[t * 8 + j] = base + loc[j];
    cnt[t * 8 + j] = 0;
  }
  // wsym[p][j] = W[k(v,w)][j] + W[k(w,v)][j] for unordered pair p (v<w)
  if (t < NOFF * VV) {
    int p = t / 9, j = t - p * 9;
    int v = 0, rem = p;
    while (rem >= 8 - v) { rem -= 8 - v; ++v; }
    int w = v + 1 + rem;
    int k1 = v * 8 + (w - 1);   // ordered (v,w), w>v
    int k2 = w * 8 + v;         // ordered (w,v), v<w
    wsym[p * 9 + j] = W_vs[k1 * 9 + j] + W_vs[k2 * 9 + j];
  }
}

// scatter voxels into bucket-sorted order; store (x,y,z,origIdx)
__global__ __launch_bounds__(256)
void k_scatter(const int* __restrict__ coords, const int* __restrict__ offs,
               int* __restrict__ cnt, int4* __restrict__ cvox, int n) {
  int i = blockIdx.x * 256 + threadIdx.x;
  if (i >= n) return;
  int x = coords[i * 4 + 1], y = coords[i * 4 + 2], z = coords[i * 4 + 3];
  int key = bucket_key(x, y, z);
  int rank = atomicAdd(&cnt[key], 1);
  cvox[offs[key] + rank] = make_int4(x, y, z, i);
}

// ---------------- main: 4 lanes/voxel, bucket-sorted, XCD-chunked, padded-fp16 map ----------------
// Plain __launch_bounds__(256): min-waves clamp spills to scratch (R4 lesson).
// R10: 64B-padded texels -> 1x b128 load per corner (36 VMEM/lane, was 108);
// symmetrized 36-pair logit matvec (108 FMA, was 216).
__global__ __launch_bounds__(256)
void vf_main4p(const int4* __restrict__ cvox,
               const uint4* __restrict__ tf,
               const float* __restrict__ proj_feat,
               const float* __restrict__ proj_img,
               const float* __restrict__ origin,
               const float* __restrict__ wsym,
               const float* __restrict__ b_vs,
               const float* __restrict__ voxel_size,
               const int* __restrict__ scale,
               const int* __restrict__ im_h_p,
               const int* __restrict__ im_w_p,
               float* __restrict__ out,
               double* __restrict__ partials,
               int n) {
  __shared__ float sPF[VV * 12], sPI[VV * 12], sB[VV], sW8b[NOFF];
  __shared__ float2 sWp2[NOFF * 4];
  __shared__ double sRed[3][4];

  int tid = threadIdx.x;
  for (int t = tid; t < VV * 12; t += 256) {
    int v = t / 12, r = t - v * 12;
    sPF[t] = proj_feat[v * 16 + r];
    sPI[t] = proj_img[v * 16 + r];
  }
  // lane lr reads logit cols {2lr, 2lr+1} as float2; col 8 broadcast
  for (int t = tid; t < NOFF * 4; t += 256) {
    int p = t >> 2, l2 = t & 3;
    sWp2[t] = make_float2(wsym[p * 9 + 2 * l2], wsym[p * 9 + 2 * l2 + 1]);
  }
  if (tid < NOFF) sW8b[tid] = wsym[tid * 9 + 8];
  if (tid < VV) sB[tid] = b_vs[tid];
  __syncthreads();

  // bijective XCD-chunked swizzle: consecutive data chunks -> one XCD
  int nb = gridDim.x;
  int q = nb >> 3, r8 = nb & 7;
  int xcd = blockIdx.x & 7, idx = blockIdx.x >> 3;
  int sb = (xcd < r8 ? xcd * (q + 1) : r8 * (q + 1) + (xcd - r8) * q) + idx;

  int lr = tid & 3;       // lane-in-quad: channels [6*lr, 6*lr+6), corners {2*lr, 2*lr+1}
  int vq = tid >> 2;      // local voxel 0..63
  int slot = sb * 64 + vq;
  bool active = slot < n;

  half2_t f[VV][CPL / 2];   // packed fp16 features
  int mkbits = 0;           // visibility bitmask, bit v
  float msum = 0.f, zmean = 0.f;
  int i0 = 0;

  if (active) {
    int4 pc = cvox[slot];
    i0 = pc.w;
    float vs = voxel_size[0];
    float half = ldexpf(0.5f * vs, scale[0]);
    float wxp = (float)pc.x * vs + origin[0];
    float wyp = (float)pc.y * vs + origin[1];
    float wzp = (float)pc.z * vs + origin[2];
    float imw1 = (float)(im_w_p[0] - 1), imh1 = (float)(im_h_p[0] - 1);
    float cx2 = 2.f / imw1;     // |2(X/Z)/imw1 - 1| <= 1.1  <=>  |X*cx2 - Z| <= 1.1*Z  (Z>0)
    float cy2 = 2.f / imh1;
    float s1 = (lr & 1) ? -1.f : 1.f;
    float s2 = (lr & 2) ? -1.f : 1.f;
    float zsum = 0.f;

#pragma unroll
    for (int v = 0; v < VV; ++v) {
      const float* M = &sPF[v * 12];
      float px = M[0] * wxp + M[1] * wyp + M[2] * wzp + M[3];
      float py = M[4] * wxp + M[5] * wyp + M[6] * wzp + M[7];
      float pz = M[8] * wxp + M[9] * wyp + M[10] * wzp + M[11];
      const float* P = &sPI[v * 12];
      float qx = P[0] * wxp + P[1] * wyp + P[2] * wzp + P[3];
      float qy = P[4] * wxp + P[5] * wyp + P[6] * wzp + P[7];
      float qz = P[8] * wxp + P[9] * wyp + P[10] * wzp + P[11];
      float h0x = P[0] * half, h1x = P[1] * half, h2x = P[2] * half;
      float h0y = P[4] * half, h1y = P[5] * half, h2y = P[6] * half;
      float h0z = P[8] * half, h1z = P[9] * half, h2z = P[10] * half;

      // two corners per lane (divide-free test), OR over quad
      float Xc = qx + s1 * h1x + s2 * h2x;
      float Yc = qy + s1 * h1y + s2 * h2y;
      float Zc = qz + s1 * h1z + s2 * h2z;
      int mbit = 0;
      {
        float X = Xc + h0x, Y = Yc + h0y, Z = Zc + h0z;
        if (Z > 0.f && fabsf(X * cx2 - Z) <= 1.1f * Z && fabsf(Y * cy2 - Z) <= 1.1f * Z) mbit = 1;
      }
      {
        float X = Xc - h0x, Y = Yc - h0y, Z = Zc - h0z;
        if (Z > 0.f && fabsf(X * cx2 - Z) <= 1.1f * Z && fabsf(Y * cy2 - Z) <= 1.1f * Z) mbit = 1;
      }
      mbit |= __shfl_xor(mbit, 1);
      mbit |= __shfl_xor(mbit, 2);
      float mkv = mbit ? 1.f : 0.f;
      mkbits |= mbit << v;
      zsum += pz * mkv;
      msum += mkv;

      float rpz = 1.f / pz;
      float x = fminf(fmaxf(px * rpz, 0.f), (float)(WFF - 1));
      float y = fminf(fmaxf(py * rpz, 0.f), (float)(HFF - 1));
      float x0f = floorf(x), y0f = floorf(y);
      float fxv = x - x0f, fyv = y - y0f;
      int x0 = (int)x0f, y0 = (int)y0f;
      x0 = min(max(x0, 0), WFF - 1);
      y0 = min(max(y0, 0), HFF - 1);
      int x1 = min(x0 + 1, WFF - 1), y1 = min(y0 + 1, HFF - 1);
      // uint4 units: texel stride 4; lane slot +lr -> 16B-aligned b128 loads
      int base16 = ((v * HFF + y0) * WFF + x0) * 4 + lr;
      int dx4 = (x1 - x0) * 4;
      int dy4 = (y1 - y0) * WFF * 4;
      float w00 = (1.f - fxv) * (1.f - fyv) * mkv;
      float w01 = fxv * (1.f - fyv) * mkv;
      float w10 = (1.f - fxv) * fyv * mkv;
      float w11 = fxv * fyv * mkv;
      half2_t W00 = pack2(w00, w00);
      half2_t W01 = pack2(w01, w01);
      half2_t W10 = pack2(w10, w10);
      half2_t W11 = pack2(w11, w11);

      const uint4* bp = tf + base16;
      H2x4 A = __builtin_bit_cast(H2x4, bp[0]);
      H2x4 B = __builtin_bit_cast(H2x4, bp[dx4]);
      H2x4 C = __builtin_bit_cast(H2x4, bp[dy4]);
      H2x4 D = __builtin_bit_cast(H2x4, bp[dx4 + dy4]);
#pragma unroll
      for (int j = 0; j < CPL / 2; ++j)
        f[v][j] = A.h[j] * W00 + B.h[j] * W01 + C.h[j] * W10 + D.h[j] * W11;
    }
    zmean = zsum / (msum + 1e-10f);
  } else {
#pragma unroll
    for (int v = 0; v < VV; ++v)
#pragma unroll
      for (int j = 0; j < CPL / 2; ++j) f[v][j] = half2_t{0, 0};
  }

  // ---- partial gram over this lane's 6 channels (fp16 dot2, fp32 accum) ----
  float gram[NPAIR];
  {
    int p = 0;
#pragma unroll
    for (int v = 0; v < VV; ++v)
#pragma unroll
      for (int w = v; w < VV; ++w, ++p) {
        float s = 0.f;
#pragma unroll
        for (int j = 0; j < CPL / 2; ++j) s = dot2acc(f[v][j], f[w][j], s);
        gram[p] = s;
      }
  }
#pragma unroll
  for (int p = 0; p < NPAIR; ++p) {
    gram[p] += __shfl_xor(gram[p], 1);
    gram[p] += __shfl_xor(gram[p], 2);
  }

  if (active) {
    float inv[VV];
#pragma unroll
    for (int v = 0; v < VV; ++v) inv[v] = 1.f / (sqrtf(gram[triidx(v, v)]) + 1e-10f);

    // symmetrized logit matvec over 36 unordered pairs; lane lr owns cols {2lr,2lr+1}, col 8 all
    float l0 = 0.f, l1 = 0.f, l2 = 0.f;
    int pp = 0;
#pragma unroll
    for (int v = 0; v < VV; ++v) {
#pragma unroll
      for (int w = v + 1; w < VV; ++w, ++pp) {
        float s = gram[triidx(v, w)] * inv[v] * inv[w];
        float2 wp = sWp2[pp * 4 + lr];
        l0 += s * wp.x;
        l1 += s * wp.y;
        l2 += s * sW8b[pp];
      }
    }
    int qb = (tid & 63) & ~3;
    float logit[VV];
    logit[0] = __shfl(l0, qb + 0); logit[1] = __shfl(l1, qb + 0);
    logit[2] = __shfl(l0, qb + 1); logit[3] = __shfl(l1, qb + 1);
    logit[4] = __shfl(l0, qb + 2); logit[5] = __shfl(l1, qb + 2);
    logit[6] = __shfl(l0, qb + 3); logit[7] = __shfl(l1, qb + 3);
    logit[8] = l2;
#pragma unroll
    for (int j = 0; j < VV; ++j) logit[j] += sB[j];

    float mx = logit[0];
#pragma unroll
    for (int j = 1; j < VV; ++j) mx = fmaxf(mx, logit[j]);
    float wt[VV], se = 0.f;
#pragma unroll
    for (int j = 0; j < VV; ++j) {
      wt[j] = __expf(logit[j] - mx);
      se += wt[j];
    }
    float rse = 1.f / se;
#pragma unroll
    for (int j = 0; j < VV; ++j) wt[j] = ((mkbits >> j) & 1) ? wt[j] * rse : 0.f;

    // fused features: packed fp16 accumulate, fp32 store
    half2_t acc[CPL / 2];
#pragma unroll
    for (int j = 0; j < CPL / 2; ++j) acc[j] = half2_t{0, 0};
#pragma unroll
    for (int v = 0; v < VV; ++v) {
      half2_t wv = pack2(wt[v], wt[v]);
#pragma unroll
      for (int j = 0; j < CPL / 2; ++j) acc[j] += f[v][j] * wv;
    }
    float* fvrow = out + (size_t)i0 * 25 + CPL * lr;
#pragma unroll
    for (int j = 0; j < CPL / 2; ++j) {
      fvrow[2 * j + 0] = (float)acc[j][0];
      fvrow[2 * j + 1] = (float)acc[j][1];
    }
    if (lr == 3) out[(size_t)i0 * 25 + CC] = zmean;  // stash zmean; znorm rewrites
    float* vwrow = out + (size_t)n * 25 + (size_t)i0 * 9;
    vwrow[lr] = wt[lr];
    vwrow[lr + 4] = wt[lr + 4];
    if (lr == 0) vwrow[8] = wt[8];
    if (lr == 1) out[(size_t)n * 34 + i0] = msum;
  }

  // ---- fused per-block z statistics (one contribution per voxel, lr==0) ----
  float zm = (active && lr == 0) ? zmean : 0.f;
  bool pos = zm > 0.f;
  double s = pos ? (double)zm : 0.0;
  double ss = pos ? (double)zm * (double)zm : 0.0;
  double cn = pos ? 1.0 : 0.0;
#pragma unroll
  for (int off = 32; off > 0; off >>= 1) {
    s += __shfl_down(s, off);
    ss += __shfl_down(ss, off);
    cn += __shfl_down(cn, off);
  }
  int wid = tid >> 6, lane = tid & 63;
  if (lane == 0) { sRed[0][wid] = s; sRed[1][wid] = ss; sRed[2][wid] = cn; }
  __syncthreads();
  if (tid == 0) {
    double S = 0, SS = 0, CN = 0;
    for (int w2 = 0; w2 < 4; ++w2) { S += sRed[0][w2]; SS += sRed[1][w2]; CN += sRed[2][w2]; }
    partials[blockIdx.x * 3 + 0] = S;
    partials[blockIdx.x * 3 + 1] = SS;
    partials[blockIdx.x * 3 + 2] = CN;
  }
}

// ---- tier A: znorm with fused (redundant per-block) mu/sd reduce — deterministic ----
__global__ __launch_bounds__(256)
void vf_znorm_fused(float* __restrict__ out, const double* __restrict__ partials,
                    int nbq, int n) {
  __shared__ double sh[3][4];
  __shared__ float sMuSd[2];
  double s = 0, ss = 0, cn = 0;
  for (int b = threadIdx.x; b < nbq; b += 256) {
    s += partials[b * 3 + 0];
    ss += partials[b * 3 + 1];
    cn += partials[b * 3 + 2];
  }
#pragma unroll
  for (int off = 32; off > 0; off >>= 1) {
    s += __shfl_down(s, off);
    ss += __shfl_down(ss, off);
    cn += __shfl_down(cn, off);
  }
  int wid = threadIdx.x >> 6, lane = threadIdx.x & 63;
  if (lane == 0) { sh[0][wid] = s; sh[1][wid] = ss; sh[2][wid] = cn; }
  __syncthreads();
  if (threadIdx.x == 0) {
    double S = 0, SS = 0, CN = 0;
    for (int w2 = 0; w2 < 4; ++w2) { S += sh[0][w2]; SS += sh[1][w2]; CN += sh[2][w2]; }
    double cnt = CN < 1.0 ? 1.0 : CN;
    double mu = S / cnt;
    double ssd = SS - 2.0 * mu * S + mu * mu * CN;
    if (ssd < 0.0) ssd = 0.0;
    sMuSd[0] = (float)mu;
    sMuSd[1] = (float)(sqrt(ssd) + 1e-5);
  }
  __syncthreads();
  float mu = sMuSd[0], sd = sMuSd[1];
  int i = blockIdx.x * 256 + threadIdx.x;
  if (i >= n) return;
  float z = out[(size_t)i * 25 + CC];
  out[(size_t)i * 25 + CC] = (z > 0.f) ? (z - mu) / sd : 0.f;
}

// ================= tier-B fallback (no permutation, fp32 map) =================
__global__ __launch_bounds__(256)
void vf_transpose(const float* __restrict__ feats, float* __restrict__ tf, int total) {
  int i = blockIdx.x * 256 + threadIdx.x;
  if (i >= total) return;
  int v = i / HW;
  int hw = i - v * HW;
  const float* s = feats + (size_t)v * CC * HW + hw;
  float4* d = (float4*)(tf + (size_t)i * CC);
#pragma unroll
  for (int c4 = 0; c4 < CC / 4; ++c4) {
    float4 o;
    o.x = s[(size_t)(c4 * 4 + 0) * HW];
    o.y = s[(size_t)(c4 * 4 + 1) * HW];
    o.z = s[(size_t)(c4 * 4 + 2) * HW];
    o.w = s[(size_t)(c4 * 4 + 3) * HW];
    d[c4] = o;
  }
}

__global__ __launch_bounds__(256)
void k_zpart(const float* __restrict__ out, double* __restrict__ partials, int n) {
  __shared__ double sRed[3][4];
  int i = blockIdx.x * 256 + threadIdx.x;
  float zm = (i < n) ? out[(size_t)i * 25 + CC] : 0.f;
  bool pos = zm > 0.f;
  double s = pos ? (double)zm : 0.0;
  double ss = pos ? (double)zm * (double)zm : 0.0;
  double cn = pos ? 1.0 : 0.0;
#pragma unroll
  for (int off = 32; off > 0; off >>= 1) {
    s += __shfl_down(s, off);
    ss += __shfl_down(ss, off);
    cn += __shfl_down(cn, off);
  }
  int wid = threadIdx.x >> 6, lane = threadIdx.x & 63;
  if (lane == 0) { sRed[0][wid] = s; sRed[1][wid] = ss; sRed[2][wid] = cn; }
  __syncthreads();
  if (threadIdx.x == 0) {
    double S = 0, SS = 0, CN = 0;
    for (int w2 = 0; w2 < 4; ++w2) { S += sRed[0][w2]; SS += sRed[1][w2]; CN += sRed[2][w2]; }
    partials[blockIdx.x * 3 + 0] = S;
    partials[blockIdx.x * 3 + 1] = SS;
    partials[blockIdx.x * 3 + 2] = CN;
  }
}

__global__ __launch_bounds__(256)
void vf_reduce(const double* __restrict__ partials, int nb, float* __restrict__ musd) {
  __shared__ double sh[3][4];
  double s = 0, ss = 0, cn = 0;
  for (int b = threadIdx.x; b < nb; b += 256) {
    s += partials[b * 3 + 0];
    ss += partials[b * 3 + 1];
    cn += partials[b * 3 + 2];
  }
#pragma unroll
  for (int off = 32; off > 0; off >>= 1) {
    s += __shfl_down(s, off);
    ss += __shfl_down(ss, off);
    cn += __shfl_down(cn, off);
  }
  int wid = threadIdx.x >> 6, lane = threadIdx.x & 63;
  if (lane == 0) { sh[0][wid] = s; sh[1][wid] = ss; sh[2][wid] = cn; }
  __syncthreads();
  if (threadIdx.x == 0) {
    double S = 0, SS = 0, CN = 0;
    for (int w2 = 0; w2 < 4; ++w2) { S += sh[0][w2]; SS += sh[1][w2]; CN += sh[2][w2]; }
    double cnt = CN < 1.0 ? 1.0 : CN;
    double mu = S / cnt;
    double ssd = SS - 2.0 * mu * S + mu * mu * CN;
    if (ssd < 0.0) ssd = 0.0;
    double sd = sqrt(ssd) + 1e-5;
    musd[0] = (float)mu;
    musd[1] = (float)sd;
  }
}

__global__ __launch_bounds__(256)
void vf_znorm(float* __restrict__ out, const float* __restrict__ musd, int n) {
  int i = blockIdx.x * 256 + threadIdx.x;
  if (i >= n) return;
  float z = out[(size_t)i * 25 + CC];
  float mu = musd[0], sd = musd[1];
  out[(size_t)i * 25 + CC] = (z > 0.f) ? (z - mu) / sd : 0.f;
}

__global__ __launch_bounds__(256)
void vf_main4(const int* __restrict__ coords,
              const float* __restrict__ tfeats,
              const float* __restrict__ proj_feat,
              const float* __restrict__ proj_img,
              const float* __restrict__ origin,
              const float* __restrict__ W_vs,
              const float* __restrict__ b_vs,
              const float* __restrict__ voxel_size,
              const int* __restrict__ scale,
              const int* __restrict__ im_h_p,
              const int* __restrict__ im_w_p,
              float* __restrict__ out,
              int n) {
  __shared__ float sPF[VV * 12], sPI[VV * 12], sW[SIMDIM * VV], sB[VV];
  __shared__ float4 sFV4[64 * 25 / 4 + 1];
  __shared__ float4 sVW4[64 * 9 / 4];
  __shared__ float sCNT[64];
  float* sFV = (float*)sFV4;
  float* sVW = (float*)sVW4;

  int tid = threadIdx.x;
  for (int t = tid; t < VV * 12; t += 256) {
    int v = t / 12, r = t - v * 12;
    sPF[t] = proj_feat[v * 16 + r];
    sPI[t] = proj_img[v * 16 + r];
  }
  for (int t = tid; t < SIMDIM * VV; t += 256) sW[t] = W_vs[t];
  if (tid < VV) sB[tid] = b_vs[tid];
  __syncthreads();

  int lr = tid & 3;
  int vloc = tid >> 2;
  int vox = blockIdx.x * 64 + vloc;
  bool active = vox < n;
  float zmean = 0.f;

  float f[VV][CPL];
  float mk[VV];
  float msum = 0.f;

  if (active) {
    float vs = voxel_size[0];
    float half = ldexpf(0.5f * vs, scale[0]);
    float wxp = (float)coords[vox * 4 + 1] * vs + origin[0];
    float wyp = (float)coords[vox * 4 + 2] * vs + origin[1];
    float wzp = (float)coords[vox * 4 + 3] * vs + origin[2];
    float imw1 = (float)(im_w_p[0] - 1), imh1 = (float)(im_h_p[0] - 1);
    float zsum = 0.f;

#pragma unroll
    for (int v = 0; v < VV; ++v) {
      const float* M = &sPF[v * 12];
      float px = M[0] * wxp + M[1] * wyp + M[2] * wzp + M[3];
      float py = M[4] * wxp + M[5] * wyp + M[6] * wzp + M[7];
      float pz = M[8] * wxp + M[9] * wyp + M[10] * wzp + M[11];
      const float* P = &sPI[v * 12];
      float qx = P[0] * wxp + P[1] * wyp + P[2] * wzp + P[3];
      float qy = P[4] * wxp + P[5] * wyp + P[6] * wzp + P[7];
      float qz = P[8] * wxp + P[9] * wyp + P[10] * wzp + P[11];
      float h0x = P[0] * half, h1x = P[1] * half, h2x = P[2] * half;
      float h0y = P[4] * half, h1y = P[5] * half, h2y = P[6] * half;
      float h0z = P[8] * half, h1z = P[9] * half, h2z = P[10] * half;
      bool m = false;
#pragma unroll
      for (int k = 0; k < 8; ++k) {
        float s0 = (k & 1) ? -1.f : 1.f;
        float s1 = (k & 2) ? -1.f : 1.f;
        float s2 = (k & 4) ? -1.f : 1.f;
        float X = qx + s0 * h0x + s1 * h1x + s2 * h2x;
        float Y = qy + s0 * h0y + s1 * h1y + s2 * h2y;
        float Z = qz + s0 * h0z + s1 * h1z + s2 * h2z;
        float gxc = 2.f * (X / Z) / imw1 - 1.f;
        float gyc = 2.f * (Y / Z) / imh1 - 1.f;
        m = m || (fabsf(gxc) <= 1.1f && fabsf(gyc) <= 1.1f && Z > 0.f);
      }
      float mkv = m ? 1.f : 0.f;
      mk[v] = mkv;
      zsum += pz * mkv;
      msum += mkv;

      float x = fminf(fmaxf(px / pz, 0.f), (float)(WFF - 1));
      float y = fminf(fmaxf(py / pz, 0.f), (float)(HFF - 1));
      float x0f = floorf(x), y0f = floorf(y);
      float fxv = x - x0f, fyv = y - y0f;
      int x0 = (int)x0f, y0 = (int)y0f;
      x0 = min(max(x0, 0), WFF - 1);
      y0 = min(max(y0, 0), HFF - 1);
      int x1 = min(x0 + 1, WFF - 1), y1 = min(y0 + 1, HFF - 1);
      int base = ((v * HFF + y0) * WFF + x0) * CC + CPL * lr;
      int dxo = (x1 - x0) * CC;
      int dyo = (y1 - y0) * WFF * CC;
      float w00 = (1.f - fxv) * (1.f - fyv) * mkv;
      float w01 = fxv * (1.f - fyv) * mkv;
      float w10 = (1.f - fxv) * fyv * mkv;
      float w11 = fxv * fyv * mkv;

      const float* bp = tfeats + base;
#pragma unroll
      for (int j = 0; j < CPL / 2; ++j) {
        float2 a = *(const float2*)(bp + 2 * j);
        float2 b = *(const float2*)(bp + dxo + 2 * j);
        float2 c = *(const float2*)(bp + dyo + 2 * j);
        float2 d = *(const float2*)(bp + dxo + dyo + 2 * j);
        f[v][2 * j + 0] = w00 * a.x + w01 * b.x + w10 * c.x + w11 * d.x;
        f[v][2 * j + 1] = w00 * a.y + w01 * b.y + w10 * c.y + w11 * d.y;
      }
    }
    zmean = zsum / (msum + 1e-10f);
  } else {
#pragma unroll
    for (int v = 0; v < VV; ++v) {
      mk[v] = 0.f;
#pragma unroll
      for (int c = 0; c < CPL; ++c) f[v][c] = 0.f;
    }
  }

  float gram[NPAIR];
  {
    int p = 0;
#pragma unroll
    for (int v = 0; v < VV; ++v)
#pragma unroll
      for (int w = v; w < VV; ++w, ++p) {
        float s = 0.f;
#pragma unroll
        for (int c = 0; c < CPL; ++c) s += f[v][c] * f[w][c];
        gram[p] = s;
      }
  }
#pragma unroll
  for (int p = 0; p < NPAIR; ++p) {
    gram[p] += __shfl_xor(gram[p], 1);
    gram[p] += __shfl_xor(gram[p], 2);
  }

  if (active) {
    float inv[VV];
#pragma unroll
    for (int v = 0; v < VV; ++v) inv[v] = 1.f / (sqrtf(gram[triidx(v, v)]) + 1e-10f);

    float logit[VV];
#pragma unroll
    for (int j = 0; j < VV; ++j) logit[j] = sB[j];
    int k = 0;
#pragma unroll
    for (int v = 0; v < VV; ++v) {
#pragma unroll
      for (int w = 0; w < VV; ++w) {
        if (w == v) continue;
        int a = v < w ? v : w, b2 = v < w ? w : v;
        float s = gram[triidx(a, b2)] * inv[v] * inv[w];
#pragma unroll
        for (int j = 0; j < VV; ++j) logit[j] += s * sW[k * VV + j];
        ++k;
      }
    }

    float mx = logit[0];
#pragma unroll
    for (int j = 1; j < VV; ++j) mx = fmaxf(mx, logit[j]);
    float wt[VV], se = 0.f;
#pragma unroll
    for (int j = 0; j < VV; ++j) {
      wt[j] = __expf(logit[j] - mx);
      se += wt[j];
    }
    float rse = 1.f / se;
#pragma unroll
    for (int j = 0; j < VV; ++j) wt[j] = wt[j] * rse * mk[j];

#pragma unroll
    for (int c = 0; c < CPL; ++c) {
      float acc = 0.f;
#pragma unroll
      for (int v = 0; v < VV; ++v) acc += wt[v] * f[v][c];
      sFV[vloc * 25 + CPL * lr + c] = acc;
    }
    if (lr == 0) {
      sFV[vloc * 25 + CC] = zmean;
#pragma unroll
      for (int j = 0; j < VV; ++j) sVW[vloc * 9 + j] = wt[j];
      sCNT[vloc] = msum;
    }
  }
  __syncthreads();

  int vb = blockIdx.x * 64;
  int cv = min(64, n - vb);
  if (cv == 64) {
    float4* dfv = (float4*)(out + (size_t)vb * 25);
    for (int t = tid; t < 400; t += 256) dfv[t] = sFV4[t];
    float4* dvw = (float4*)(out + (size_t)n * 25 + (size_t)vb * 9);
    for (int t = tid; t < 144; t += 256) dvw[t] = sVW4[t];
    if (tid < 64) out[(size_t)n * 34 + vb + tid] = sCNT[tid];
  } else if (cv > 0) {
    for (int t = tid; t < cv * 25; t += 256) out[(size_t)vb * 25 + t] = sFV[t];
    for (int t = tid; t < cv * 9; t += 256) out[(size_t)n * 25 + (size_t)vb * 9 + t] = sVW[t];
    if (tid < cv) out[(size_t)n * 34 + vb + tid] = sCNT[tid];
  }
}

extern "C" void kernel_launch(void* const* d_in, const int* in_sizes, int n_in,
                              void* d_out, int out_size, void* d_ws, size_t ws_size,
                              hipStream_t stream) {
  const int* coords = (const int*)d_in[0];
  const float* feats = (const float*)d_in[1];
  const float* proj_feat = (const float*)d_in[2];
  const float* proj_img = (const float*)d_in[3];
  const float* origin = (const float*)d_in[4];
  const float* W_vs = (const float*)d_in[5];
  const float* b_vs = (const float*)d_in[6];
  const float* voxel_size = (const float*)d_in[7];
  const int* scale = (const int*)d_in[8];
  const int* im_h = (const int*)d_in[9];
  const int* im_w = (const int*)d_in[10];

  int n = in_sizes[0] / 4;
  int nbq = (n + 63) / 64;          // main blocks (64 voxels each)
  int nbz = (n + 255) / 256;        // per-voxel grids
  int nbt = (VV * HW + 255) / 256;  // transpose blocks
  int nbp = nbq > nbz ? nbq : nbz;  // partials sizing

  // workspace layout
  size_t off = 0;
  float* musd = (float*)d_ws;                      off += 256;
  int* hist = (int*)((char*)d_ws + off);           off += NBKT_PAD * 4;
  int* offs = (int*)((char*)d_ws + off);           off += NBKT_PAD * 4;
  int* cnt  = (int*)((char*)d_ws + off);           off += NBKT_PAD * 4;
  float* wsym = (float*)((char*)d_ws + off);       off += NOFF * VV * 4;
  off = (off + 255) & ~(size_t)255;
  double* partials = (double*)((char*)d_ws + off); off += (size_t)nbp * 3 * 8;
  off = (off + 255) & ~(size_t)255;
  int4* cvox = (int4*)((char*)d_ws + off);         size_t cvox_off = off; off += (size_t)n * 16;
  off = (off + 255) & ~(size_t)255;
  uint4* tf16 = (uint4*)((char*)d_ws + off);
  size_t tf16_bytes = (size_t)VV * HW * 64;   // padded 64B texels
  size_t need_full = off + tf16_bytes;
  size_t tf32_bytes = (size_t)VV * HW * CC * 4;

  if (ws_size >= need_full) {
    // ---- tier A: bucket-sorted, XCD-chunked, padded-fp16 map, 6 dispatches ----
    // zero hist only (cnt zeroed by k_scan; d_ws is poisoned 0xAA — R3 lesson)
    (void)hipMemsetAsync(hist, 0, (size_t)NBKT_PAD * 4, stream);
    k_t16_hist<<<dim3(nbt + nbz), dim3(256), 0, stream>>>(feats, tf16, coords, hist, n, nbt);
    k_scan<<<dim3(1), dim3(256), 0, stream>>>(hist, offs, cnt, W_vs, wsym);
    k_scatter<<<dim3(nbz), dim3(256), 0, stream>>>(coords, offs, cnt, cvox, n);
    vf_main4p<<<dim3(nbq), dim3(256), 0, stream>>>(
        cvox, tf16, proj_feat, proj_img, origin, wsym, b_vs, voxel_size,
        scale, im_h, im_w, (float*)d_out, partials, n);
    vf_znorm_fused<<<dim3(nbz), dim3(256), 0, stream>>>((float*)d_out, partials, nbq, n);
  } else if (ws_size >= cvox_off + tf32_bytes) {
    // ---- tier B: no permutation, fp32 map ----
    float* tfb = (float*)((char*)d_ws + cvox_off);
    vf_transpose<<<dim3(nbt), dim3(256), 0, stream>>>(feats, tfb, VV * HW);
    vf_main4<<<dim3(nbq), dim3(256), 0, stream>>>(
        coords, tfb, proj_feat, proj_img, origin, W_vs, b_vs, voxel_size,
        scale, im_h, im_w, (float*)d_out, n);
    k_zpart<<<dim3(nbz), dim3(256), 0, stream>>>((const float*)d_out, partials, n);
    vf_reduce<<<dim3(1), dim3(256), 0, stream>>>(partials, nbz, musd);
    vf_znorm<<<dim3(nbz), dim3(256), 0, stream>>>((float*)d_out, musd, n);
  }
}

// Round 11
// 130.201 us; speedup vs baseline: 1.6339x; 1.2095x over previous
//
#include <hip/hip_runtime.h>

#define VV 9
#define CC 24
#define HFF 120
#define WFF 160
#define HW (HFF*WFF)
#define NPAIR 45
#define NOFF 36    // unordered off-diagonal pairs
#define SIMDIM 72
#define CPL 6      // channels per lane (quad scheme)
#define NBKT 1728  // 12x12x12 spatial buckets (8^3 voxel cells)
#define NBKT_PAD 2048

typedef _Float16 half2_t __attribute__((ext_vector_type(2)));
struct H2x4 { half2_t h[4]; };

__device__ __host__ __forceinline__ constexpr int triidx(int a, int b) {
  return a * VV - a * (a - 1) / 2 + (b - a);
}

__device__ __forceinline__ half2_t pack2(float a, float b) {
  return __builtin_bit_cast(half2_t, __builtin_amdgcn_cvt_pkrtz(a, b));
}

__device__ __forceinline__ float dot2acc(half2_t a, half2_t b, float c) {
#if __has_builtin(__builtin_amdgcn_fdot2)
  return __builtin_amdgcn_fdot2(a, b, c, false);
#else
  return c + (float)a[0] * (float)b[0] + (float)a[1] * (float)b[1];
#endif
}

__device__ __forceinline__ int bucket_key(int x, int y, int z) {
  int kx = min(max(x, 0) >> 3, 11);
  int ky = min(max(y, 0) >> 3, 11);
  int kz = min(max(z, 0) >> 3, 11);
  return (kx * 12 + ky) * 12 + kz;
}

// ---------------- fused: (V,C,H,W) f32 -> (V,H,W,C16pad) f16 transpose + coord histogram ----------------
// Texel = 64 B: 4 slots of 16 B (lane lr's 6 channels in first 12 B + 4 B pad) -> b128 gather loads.
__global__ __launch_bounds__(256)
void k_t16_hist(const float* __restrict__ feats, uint4* __restrict__ tf,
                const int* __restrict__ coords, int* __restrict__ hist,
                int n, int nbt) {
  int b = blockIdx.x;
  if (b < nbt) {
    int i = b * 256 + threadIdx.x;
    if (i >= VV * HW) return;
    int v = i / HW;
    int hw = i - v * HW;
    const float* s = feats + (size_t)v * CC * HW + hw;
    uint4* d = tf + (size_t)i * 4;
#pragma unroll
    for (int lr = 0; lr < 4; ++lr) {
      half2_t t0 = pack2(s[(size_t)(6 * lr + 0) * HW], s[(size_t)(6 * lr + 1) * HW]);
      half2_t t1 = pack2(s[(size_t)(6 * lr + 2) * HW], s[(size_t)(6 * lr + 3) * HW]);
      half2_t t2 = pack2(s[(size_t)(6 * lr + 4) * HW], s[(size_t)(6 * lr + 5) * HW]);
      H2x4 o;
      o.h[0] = t0; o.h[1] = t1; o.h[2] = t2; o.h[3] = half2_t{0, 0};
      d[lr] = __builtin_bit_cast(uint4, o);
    }
  } else {
    int i = (b - nbt) * 256 + threadIdx.x;
    if (i >= n) return;
    int key = bucket_key(coords[i * 4 + 1], coords[i * 4 + 2], coords[i * 4 + 3]);
    atomicAdd(&hist[key], 1);
  }
}

// exclusive scan over NBKT_PAD entries + zero cnt + precompute symmetrized W pairs
// R10 BUG FIX: wsym has NOFF*VV=324 entries > 256 threads -> must be a strided loop
// (the old `if (t < 324)` left wsym[256..323] as 0xAA poison => absmax 0.15).
__global__ __launch_bounds__(256)
void k_scan(const int* __restrict__ hist, int* __restrict__ offs,
            int* __restrict__ cnt, const float* __restrict__ W_vs,
            float* __restrict__ wsym) {
  __shared__ int sh[256];
  int t = threadIdx.x;
  int loc[8];
  int s = 0;
#pragma unroll
  for (int j = 0; j < 8; ++j) loc[j] = hist[t * 8 + j];
#pragma unroll
  for (int j = 0; j < 8; ++j) { int v = loc[j]; loc[j] = s; s += v; }
  sh[t] = s;
  __syncthreads();
  for (int off = 1; off < 256; off <<= 1) {
    int v = (t >= off) ? sh[t - off] : 0;
    __syncthreads();
    sh[t] += v;
    __syncthreads();
  }
  int base = sh[t] - s;  // exclusive
#pragma unroll
  for (int j = 0; j < 8; ++j) {
    offs[t * 8 + j] = base + loc[j];
    cnt[t * 8 + j] = 0;
  }
  // wsym[p][j] = W[k(v,w)][j] + W[k(w,v)][j] for unordered pair p (v<w)
  for (int tt = t; tt < NOFF * VV; tt += 256) {
    int p = tt / 9, j = tt - p * 9;
    int v = 0, rem = p;
    while (rem >= 8 - v) { rem -= 8 - v; ++v; }
    int w = v + 1 + rem;
    int k1 = v * 8 + (w - 1);   // ordered (v,w), w>v
    int k2 = w * 8 + v;         // ordered (w,v), v<w
    wsym[p * 9 + j] = W_vs[k1 * 9 + j] + W_vs[k2 * 9 + j];
  }
}

// ---------------- scatter + visibility mask (reference formula) + z-stat partials ----------------
// cvox = int2{ x | y<<7 | z<<14 | mask9<<21, origIdx }
__global__ __launch_bounds__(256)
void k_scatter_zm(const int* __restrict__ coords, const int* __restrict__ offs,
                  int* __restrict__ cnt, int2* __restrict__ cvox,
                  const float* __restrict__ proj_feat,
                  const float* __restrict__ proj_img,
                  const float* __restrict__ origin,
                  const float* __restrict__ voxel_size,
                  const int* __restrict__ scale,
                  const int* __restrict__ im_h_p,
                  const int* __restrict__ im_w_p,
                  double* __restrict__ partials, int n) {
  __shared__ float sPFz[VV * 4], sPI[VV * 12];
  __shared__ double sRed[3][4];
  int tid = threadIdx.x;
  for (int t = tid; t < VV * 12; t += 256) {
    int v = t / 12, r = t - v * 12;
    sPI[t] = proj_img[v * 16 + r];
  }
  if (tid < VV * 4) {
    int v = tid >> 2, r = tid & 3;
    sPFz[tid] = proj_feat[v * 16 + 8 + r];   // row 2 (pz) only
  }
  __syncthreads();

  int i = blockIdx.x * 256 + tid;
  float zmean = 0.f;
  if (i < n) {
    int x = coords[i * 4 + 1], y = coords[i * 4 + 2], z = coords[i * 4 + 3];
    int key = bucket_key(x, y, z);
    int rank = atomicAdd(&cnt[key], 1);
    float vs = voxel_size[0];
    float half = ldexpf(0.5f * vs, scale[0]);
    float wxp = (float)x * vs + origin[0];
    float wyp = (float)y * vs + origin[1];
    float wzp = (float)z * vs + origin[2];
    float imw1 = (float)(im_w_p[0] - 1), imh1 = (float)(im_h_p[0] - 1);
    int mkbits = 0;
    float zsum = 0.f, msum = 0.f;
#pragma unroll
    for (int v = 0; v < VV; ++v) {
      const float* R = &sPFz[v * 4];
      float pz = R[0] * wxp + R[1] * wyp + R[2] * wzp + R[3];
      const float* P = &sPI[v * 12];
      float qx = P[0] * wxp + P[1] * wyp + P[2] * wzp + P[3];
      float qy = P[4] * wxp + P[5] * wyp + P[6] * wzp + P[7];
      float qz = P[8] * wxp + P[9] * wyp + P[10] * wzp + P[11];
      float h0x = P[0] * half, h1x = P[1] * half, h2x = P[2] * half;
      float h0y = P[4] * half, h1y = P[5] * half, h2y = P[6] * half;
      float h0z = P[8] * half, h1z = P[9] * half, h2z = P[10] * half;
      bool m = false;
#pragma unroll
      for (int k = 0; k < 8; ++k) {
        float s0 = (k & 1) ? -1.f : 1.f;
        float s1 = (k & 2) ? -1.f : 1.f;
        float s2 = (k & 4) ? -1.f : 1.f;
        float X = qx + s0 * h0x + s1 * h1x + s2 * h2x;
        float Y = qy + s0 * h0y + s1 * h1y + s2 * h2y;
        float Z = qz + s0 * h0z + s1 * h1z + s2 * h2z;
        // reference formulation (real divides) for max numerical fidelity
        float gxc = 2.f * (X / Z) / imw1 - 1.f;
        float gyc = 2.f * (Y / Z) / imh1 - 1.f;
        m = m || (fabsf(gxc) <= 1.1f && fabsf(gyc) <= 1.1f && Z > 0.f);
      }
      if (m) {
        mkbits |= 1 << v;
        zsum += pz;
        msum += 1.f;
      }
    }
    zmean = zsum / (msum + 1e-10f);
    cvox[offs[key] + rank] = make_int2(x | (y << 7) | (z << 14) | (mkbits << 21), i);
  }

  // per-block z statistics (deterministic)
  bool pos = zmean > 0.f;
  double s = pos ? (double)zmean : 0.0;
  double ss = pos ? (double)zmean * (double)zmean : 0.0;
  double cn = pos ? 1.0 : 0.0;
#pragma unroll
  for (int off = 32; off > 0; off >>= 1) {
    s += __shfl_down(s, off);
    ss += __shfl_down(ss, off);
    cn += __shfl_down(cn, off);
  }
  int wid = tid >> 6, lane = tid & 63;
  if (lane == 0) { sRed[0][wid] = s; sRed[1][wid] = ss; sRed[2][wid] = cn; }
  __syncthreads();
  if (tid == 0) {
    double S = 0, SS = 0, CN = 0;
    for (int w2 = 0; w2 < 4; ++w2) { S += sRed[0][w2]; SS += sRed[1][w2]; CN += sRed[2][w2]; }
    partials[blockIdx.x * 3 + 0] = S;
    partials[blockIdx.x * 3 + 1] = SS;
    partials[blockIdx.x * 3 + 2] = CN;
  }
}

// ---------------- main: 4 lanes/voxel, bucket-sorted, XCD-chunked, padded-fp16 map ----------------
// Plain __launch_bounds__(256): min-waves clamp spills to scratch (R4 lesson).
// R11: mask precomputed in scatter (no proj_img work here); per-block redundant mu/sd
// reduce at start; z_norm written directly (znorm pass eliminated).
__global__ __launch_bounds__(256)
void vf_main4p(const int2* __restrict__ cvox,
               const uint4* __restrict__ tf,
               const float* __restrict__ proj_feat,
               const float* __restrict__ origin,
               const float* __restrict__ wsym,
               const float* __restrict__ b_vs,
               const float* __restrict__ voxel_size,
               const int* __restrict__ scale,
               const double* __restrict__ partials,
               int nbz,
               float* __restrict__ out,
               int n) {
  __shared__ float sPF[VV * 12], sB[VV], sW8b[NOFF];
  __shared__ float2 sWp2[NOFF * 4];
  __shared__ double sRed[3][4];
  __shared__ float sMuSd[2];

  int tid = threadIdx.x;
  for (int t = tid; t < VV * 12; t += 256) {
    int v = t / 12, r = t - v * 12;
    sPF[t] = proj_feat[v * 16 + r];
  }
  for (int t = tid; t < NOFF * 4; t += 256) {
    int p = t >> 2, l2 = t & 3;
    sWp2[t] = make_float2(wsym[p * 9 + 2 * l2], wsym[p * 9 + 2 * l2 + 1]);
  }
  if (tid < NOFF) sW8b[tid] = wsym[tid * 9 + 8];
  if (tid < VV) sB[tid] = b_vs[tid];

  // redundant per-block mu/sd reduce (deterministic; partials are L2-resident)
  {
    double s = 0, ss = 0, cn = 0;
    for (int b = tid; b < nbz; b += 256) {
      s += partials[b * 3 + 0];
      ss += partials[b * 3 + 1];
      cn += partials[b * 3 + 2];
    }
#pragma unroll
    for (int off = 32; off > 0; off >>= 1) {
      s += __shfl_down(s, off);
      ss += __shfl_down(ss, off);
      cn += __shfl_down(cn, off);
    }
    int wid = tid >> 6, lane = tid & 63;
    if (lane == 0) { sRed[0][wid] = s; sRed[1][wid] = ss; sRed[2][wid] = cn; }
    __syncthreads();
    if (tid == 0) {
      double S = 0, SS = 0, CN = 0;
      for (int w2 = 0; w2 < 4; ++w2) { S += sRed[0][w2]; SS += sRed[1][w2]; CN += sRed[2][w2]; }
      double cnt2 = CN < 1.0 ? 1.0 : CN;
      double mu = S / cnt2;
      double ssd = SS - 2.0 * mu * S + mu * mu * CN;
      if (ssd < 0.0) ssd = 0.0;
      sMuSd[0] = (float)mu;
      sMuSd[1] = (float)(sqrt(ssd) + 1e-5);
    }
    __syncthreads();
  }
  float gmu = sMuSd[0], gsd = sMuSd[1];

  // bijective XCD-chunked swizzle: consecutive data chunks -> one XCD
  int nb = gridDim.x;
  int q = nb >> 3, r8 = nb & 7;
  int xcd = blockIdx.x & 7, idx = blockIdx.x >> 3;
  int sb = (xcd < r8 ? xcd * (q + 1) : r8 * (q + 1) + (xcd - r8) * q) + idx;

  int lr = tid & 3;       // lane-in-quad: channels [6*lr, 6*lr+6)
  int vq = tid >> 2;      // local voxel 0..63
  int slot = sb * 64 + vq;
  bool active = slot < n;

  half2_t f[VV][CPL / 2];   // packed fp16 features
  int mkbits = 0;
  float zmean = 0.f;
  int i0 = 0;

  if (active) {
    int2 pc = cvox[slot];
    int px_ = pc.x;
    int cx = px_ & 127, cy = (px_ >> 7) & 127, cz = (px_ >> 14) & 127;
    mkbits = (px_ >> 21) & 511;
    i0 = pc.y;
    float vs = voxel_size[0];
    float wxp = (float)cx * vs + origin[0];
    float wyp = (float)cy * vs + origin[1];
    float wzp = (float)cz * vs + origin[2];
    float zsum = 0.f;

#pragma unroll
    for (int v = 0; v < VV; ++v) {
      const float* M = &sPF[v * 12];
      float px = M[0] * wxp + M[1] * wyp + M[2] * wzp + M[3];
      float py = M[4] * wxp + M[5] * wyp + M[6] * wzp + M[7];
      float pz = M[8] * wxp + M[9] * wyp + M[10] * wzp + M[11];
      float mkv = (float)((mkbits >> v) & 1);
      zsum += pz * mkv;

      float rpz = 1.f / pz;
      float x = fminf(fmaxf(px * rpz, 0.f), (float)(WFF - 1));
      float y = fminf(fmaxf(py * rpz, 0.f), (float)(HFF - 1));
      float x0f = floorf(x), y0f = floorf(y);
      float fxv = x - x0f, fyv = y - y0f;
      int x0 = (int)x0f, y0 = (int)y0f;
      x0 = min(max(x0, 0), WFF - 1);
      y0 = min(max(y0, 0), HFF - 1);
      int x1 = min(x0 + 1, WFF - 1), y1 = min(y0 + 1, HFF - 1);
      // uint4 units: texel stride 4; lane slot +lr -> 16B-aligned b128 loads
      int base16 = ((v * HFF + y0) * WFF + x0) * 4 + lr;
      int dx4 = (x1 - x0) * 4;
      int dy4 = (y1 - y0) * WFF * 4;
      float w00 = (1.f - fxv) * (1.f - fyv) * mkv;
      float w01 = fxv * (1.f - fyv) * mkv;
      float w10 = (1.f - fxv) * fyv * mkv;
      float w11 = fxv * fyv * mkv;
      half2_t W00 = pack2(w00, w00);
      half2_t W01 = pack2(w01, w01);
      half2_t W10 = pack2(w10, w10);
      half2_t W11 = pack2(w11, w11);

      const uint4* bp = tf + base16;
      H2x4 A = __builtin_bit_cast(H2x4, bp[0]);
      H2x4 B = __builtin_bit_cast(H2x4, bp[dx4]);
      H2x4 C = __builtin_bit_cast(H2x4, bp[dy4]);
      H2x4 D = __builtin_bit_cast(H2x4, bp[dx4 + dy4]);
#pragma unroll
      for (int j = 0; j < CPL / 2; ++j)
        f[v][j] = A.h[j] * W00 + B.h[j] * W01 + C.h[j] * W10 + D.h[j] * W11;
    }
    float msum = (float)__popc(mkbits);
    zmean = zsum / (msum + 1e-10f);
  } else {
#pragma unroll
    for (int v = 0; v < VV; ++v)
#pragma unroll
      for (int j = 0; j < CPL / 2; ++j) f[v][j] = half2_t{0, 0};
  }

  // ---- partial gram over this lane's 6 channels (fp16 dot2, fp32 accum) ----
  float gram[NPAIR];
  {
    int p = 0;
#pragma unroll
    for (int v = 0; v < VV; ++v)
#pragma unroll
      for (int w = v; w < VV; ++w, ++p) {
        float s = 0.f;
#pragma unroll
        for (int j = 0; j < CPL / 2; ++j) s = dot2acc(f[v][j], f[w][j], s);
        gram[p] = s;
      }
  }
#pragma unroll
  for (int p = 0; p < NPAIR; ++p) {
    gram[p] += __shfl_xor(gram[p], 1);
    gram[p] += __shfl_xor(gram[p], 2);
  }

  if (active) {
    float inv[VV];
#pragma unroll
    for (int v = 0; v < VV; ++v) inv[v] = 1.f / (sqrtf(gram[triidx(v, v)]) + 1e-10f);

    // symmetrized logit matvec over 36 unordered pairs; lane lr owns cols {2lr,2lr+1}, col 8 all
    float l0 = 0.f, l1 = 0.f, l2 = 0.f;
    int pp = 0;
#pragma unroll
    for (int v = 0; v < VV; ++v) {
#pragma unroll
      for (int w = v + 1; w < VV; ++w, ++pp) {
        float s = gram[triidx(v, w)] * inv[v] * inv[w];
        float2 wp = sWp2[pp * 4 + lr];
        l0 += s * wp.x;
        l1 += s * wp.y;
        l2 += s * sW8b[pp];
      }
    }
    int qb = (tid & 63) & ~3;
    float logit[VV];
    logit[0] = __shfl(l0, qb + 0); logit[1] = __shfl(l1, qb + 0);
    logit[2] = __shfl(l0, qb + 1); logit[3] = __shfl(l1, qb + 1);
    logit[4] = __shfl(l0, qb + 2); logit[5] = __shfl(l1, qb + 2);
    logit[6] = __shfl(l0, qb + 3); logit[7] = __shfl(l1, qb + 3);
    logit[8] = l2;
#pragma unroll
    for (int j = 0; j < VV; ++j) logit[j] += sB[j];

    float mx = logit[0];
#pragma unroll
    for (int j = 1; j < VV; ++j) mx = fmaxf(mx, logit[j]);
    float wt[VV], se = 0.f;
#pragma unroll
    for (int j = 0; j < VV; ++j) {
      wt[j] = __expf(logit[j] - mx);
      se += wt[j];
    }
    float rse = 1.f / se;
#pragma unroll
    for (int j = 0; j < VV; ++j) wt[j] = ((mkbits >> j) & 1) ? wt[j] * rse : 0.f;

    // fused features: packed fp16 accumulate, fp32 store
    half2_t acc[CPL / 2];
#pragma unroll
    for (int j = 0; j < CPL / 2; ++j) acc[j] = half2_t{0, 0};
#pragma unroll
    for (int v = 0; v < VV; ++v) {
      half2_t wv = pack2(wt[v], wt[v]);
#pragma unroll
      for (int j = 0; j < CPL / 2; ++j) acc[j] += f[v][j] * wv;
    }
    float* fvrow = out + (size_t)i0 * 25 + CPL * lr;
#pragma unroll
    for (int j = 0; j < CPL / 2; ++j) {
      fvrow[2 * j + 0] = (float)acc[j][0];
      fvrow[2 * j + 1] = (float)acc[j][1];
    }
    // direct z_norm write (mu/sd reduced at block start)
    if (lr == 3)
      out[(size_t)i0 * 25 + CC] = (zmean > 0.f) ? (zmean - gmu) / gsd : 0.f;
    float* vwrow = out + (size_t)n * 25 + (size_t)i0 * 9;
    vwrow[lr] = wt[lr];
    vwrow[lr + 4] = wt[lr + 4];
    if (lr == 0) vwrow[8] = wt[8];
    if (lr == 1) out[(size_t)n * 34 + i0] = (float)__popc(mkbits);
  }
}

// ================= tier-B fallback (no permutation, fp32 map) =================
__global__ __launch_bounds__(256)
void vf_transpose(const float* __restrict__ feats, float* __restrict__ tf, int total) {
  int i = blockIdx.x * 256 + threadIdx.x;
  if (i >= total) return;
  int v = i / HW;
  int hw = i - v * HW;
  const float* s = feats + (size_t)v * CC * HW + hw;
  float4* d = (float4*)(tf + (size_t)i * CC);
#pragma unroll
  for (int c4 = 0; c4 < CC / 4; ++c4) {
    float4 o;
    o.x = s[(size_t)(c4 * 4 + 0) * HW];
    o.y = s[(size_t)(c4 * 4 + 1) * HW];
    o.z = s[(size_t)(c4 * 4 + 2) * HW];
    o.w = s[(size_t)(c4 * 4 + 3) * HW];
    d[c4] = o;
  }
}

__global__ __launch_bounds__(256)
void k_zpart(const float* __restrict__ out, double* __restrict__ partials, int n) {
  __shared__ double sRed[3][4];
  int i = blockIdx.x * 256 + threadIdx.x;
  float zm = (i < n) ? out[(size_t)i * 25 + CC] : 0.f;
  bool pos = zm > 0.f;
  double s = pos ? (double)zm : 0.0;
  double ss = pos ? (double)zm * (double)zm : 0.0;
  double cn = pos ? 1.0 : 0.0;
#pragma unroll
  for (int off = 32; off > 0; off >>= 1) {
    s += __shfl_down(s, off);
    ss += __shfl_down(ss, off);
    cn += __shfl_down(cn, off);
  }
  int wid = threadIdx.x >> 6, lane = threadIdx.x & 63;
  if (lane == 0) { sRed[0][wid] = s; sRed[1][wid] = ss; sRed[2][wid] = cn; }
  __syncthreads();
  if (threadIdx.x == 0) {
    double S = 0, SS = 0, CN = 0;
    for (int w2 = 0; w2 < 4; ++w2) { S += sRed[0][w2]; SS += sRed[1][w2]; CN += sRed[2][w2]; }
    partials[blockIdx.x * 3 + 0] = S;
    partials[blockIdx.x * 3 + 1] = SS;
    partials[blockIdx.x * 3 + 2] = CN;
  }
}

__global__ __launch_bounds__(256)
void vf_reduce(const double* __restrict__ partials, int nb, float* __restrict__ musd) {
  __shared__ double sh[3][4];
  double s = 0, ss = 0, cn = 0;
  for (int b = threadIdx.x; b < nb; b += 256) {
    s += partials[b * 3 + 0];
    ss += partials[b * 3 + 1];
    cn += partials[b * 3 + 2];
  }
#pragma unroll
  for (int off = 32; off > 0; off >>= 1) {
    s += __shfl_down(s, off);
    ss += __shfl_down(ss, off);
    cn += __shfl_down(cn, off);
  }
  int wid = threadIdx.x >> 6, lane = threadIdx.x & 63;
  if (lane == 0) { sh[0][wid] = s; sh[1][wid] = ss; sh[2][wid] = cn; }
  __syncthreads();
  if (threadIdx.x == 0) {
    double S = 0, SS = 0, CN = 0;
    for (int w2 = 0; w2 < 4; ++w2) { S += sh[0][w2]; SS += sh[1][w2]; CN += sh[2][w2]; }
    double cnt = CN < 1.0 ? 1.0 : CN;
    double mu = S / cnt;
    double ssd = SS - 2.0 * mu * S + mu * mu * CN;
    if (ssd < 0.0) ssd = 0.0;
    double sd = sqrt(ssd) + 1e-5;
    musd[0] = (float)mu;
    musd[1] = (float)sd;
  }
}

__global__ __launch_bounds__(256)
void vf_znorm(float* __restrict__ out, const float* __restrict__ musd, int n) {
  int i = blockIdx.x * 256 + threadIdx.x;
  if (i >= n) return;
  float z = out[(size_t)i * 25 + CC];
  float mu = musd[0], sd = musd[1];
  out[(size_t)i * 25 + CC] = (z > 0.f) ? (z - mu) / sd : 0.f;
}

__global__ __launch_bounds__(256)
void vf_main4(const int* __restrict__ coords,
              const float* __restrict__ tfeats,
              const float* __restrict__ proj_feat,
              const float* __restrict__ proj_img,
              const float* __restrict__ origin,
              const float* __restrict__ W_vs,
              const float* __restrict__ b_vs,
              const float* __restrict__ voxel_size,
              const int* __restrict__ scale,
              const int* __restrict__ im_h_p,
              const int* __restrict__ im_w_p,
              float* __restrict__ out,
              int n) {
  __shared__ float sPF[VV * 12], sPI[VV * 12], sW[SIMDIM * VV], sB[VV];
  __shared__ float4 sFV4[64 * 25 / 4 + 1];
  __shared__ float4 sVW4[64 * 9 / 4];
  __shared__ float sCNT[64];
  float* sFV = (float*)sFV4;
  float* sVW = (float*)sVW4;

  int tid = threadIdx.x;
  for (int t = tid; t < VV * 12; t += 256) {
    int v = t / 12, r = t - v * 12;
    sPF[t] = proj_feat[v * 16 + r];
    sPI[t] = proj_img[v * 16 + r];
  }
  for (int t = tid; t < SIMDIM * VV; t += 256) sW[t] = W_vs[t];
  if (tid < VV) sB[tid] = b_vs[tid];
  __syncthreads();

  int lr = tid & 3;
  int vloc = tid >> 2;
  int vox = blockIdx.x * 64 + vloc;
  bool active = vox < n;
  float zmean = 0.f;

  float f[VV][CPL];
  float mk[VV];
  float msum = 0.f;

  if (active) {
    float vs = voxel_size[0];
    float half = ldexpf(0.5f * vs, scale[0]);
    float wxp = (float)coords[vox * 4 + 1] * vs + origin[0];
    float wyp = (float)coords[vox * 4 + 2] * vs + origin[1];
    float wzp = (float)coords[vox * 4 + 3] * vs + origin[2];
    float imw1 = (float)(im_w_p[0] - 1), imh1 = (float)(im_h_p[0] - 1);
    float zsum = 0.f;

#pragma unroll
    for (int v = 0; v < VV; ++v) {
      const float* M = &sPF[v * 12];
      float px = M[0] * wxp + M[1] * wyp + M[2] * wzp + M[3];
      float py = M[4] * wxp + M[5] * wyp + M[6] * wzp + M[7];
      float pz = M[8] * wxp + M[9] * wyp + M[10] * wzp + M[11];
      const float* P = &sPI[v * 12];
      float qx = P[0] * wxp + P[1] * wyp + P[2] * wzp + P[3];
      float qy = P[4] * wxp + P[5] * wyp + P[6] * wzp + P[7];
      float qz = P[8] * wxp + P[9] * wyp + P[10] * wzp + P[11];
      float h0x = P[0] * half, h1x = P[1] * half, h2x = P[2] * half;
      float h0y = P[4] * half, h1y = P[5] * half, h2y = P[6] * half;
      float h0z = P[8] * half, h1z = P[9] * half, h2z = P[10] * half;
      bool m = false;
#pragma unroll
      for (int k = 0; k < 8; ++k) {
        float s0 = (k & 1) ? -1.f : 1.f;
        float s1 = (k & 2) ? -1.f : 1.f;
        float s2 = (k & 4) ? -1.f : 1.f;
        float X = qx + s0 * h0x + s1 * h1x + s2 * h2x;
        float Y = qy + s0 * h0y + s1 * h1y + s2 * h2y;
        float Z = qz + s0 * h0z + s1 * h1z + s2 * h2z;
        float gxc = 2.f * (X / Z) / imw1 - 1.f;
        float gyc = 2.f * (Y / Z) / imh1 - 1.f;
        m = m || (fabsf(gxc) <= 1.1f && fabsf(gyc) <= 1.1f && Z > 0.f);
      }
      float mkv = m ? 1.f : 0.f;
      mk[v] = mkv;
      zsum += pz * mkv;
      msum += mkv;

      float x = fminf(fmaxf(px / pz, 0.f), (float)(WFF - 1));
      float y = fminf(fmaxf(py / pz, 0.f), (float)(HFF - 1));
      float x0f = floorf(x), y0f = floorf(y);
      float fxv = x - x0f, fyv = y - y0f;
      int x0 = (int)x0f, y0 = (int)y0f;
      x0 = min(max(x0, 0), WFF - 1);
      y0 = min(max(y0, 0), HFF - 1);
      int x1 = min(x0 + 1, WFF - 1), y1 = min(y0 + 1, HFF - 1);
      int base = ((v * HFF + y0) * WFF + x0) * CC + CPL * lr;
      int dxo = (x1 - x0) * CC;
      int dyo = (y1 - y0) * WFF * CC;
      float w00 = (1.f - fxv) * (1.f - fyv) * mkv;
      float w01 = fxv * (1.f - fyv) * mkv;
      float w10 = (1.f - fxv) * fyv * mkv;
      float w11 = fxv * fyv * mkv;

      const float* bp = tfeats + base;
#pragma unroll
      for (int j = 0; j < CPL / 2; ++j) {
        float2 a = *(const float2*)(bp + 2 * j);
        float2 b = *(const float2*)(bp + dxo + 2 * j);
        float2 c = *(const float2*)(bp + dyo + 2 * j);
        float2 d = *(const float2*)(bp + dxo + dyo + 2 * j);
        f[v][2 * j + 0] = w00 * a.x + w01 * b.x + w10 * c.x + w11 * d.x;
        f[v][2 * j + 1] = w00 * a.y + w01 * b.y + w10 * c.y + w11 * d.y;
      }
    }
    zmean = zsum / (msum + 1e-10f);
  } else {
#pragma unroll
    for (int v = 0; v < VV; ++v) {
      mk[v] = 0.f;
#pragma unroll
      for (int c = 0; c < CPL; ++c) f[v][c] = 0.f;
    }
  }

  float gram[NPAIR];
  {
    int p = 0;
#pragma unroll
    for (int v = 0; v < VV; ++v)
#pragma unroll
      for (int w = v; w < VV; ++w, ++p) {
        float s = 0.f;
#pragma unroll
        for (int c = 0; c < CPL; ++c) s += f[v][c] * f[w][c];
        gram[p] = s;
      }
  }
#pragma unroll
  for (int p = 0; p < NPAIR; ++p) {
    gram[p] += __shfl_xor(gram[p], 1);
    gram[p] += __shfl_xor(gram[p], 2);
  }

  if (active) {
    float inv[VV];
#pragma unroll
    for (int v = 0; v < VV; ++v) inv[v] = 1.f / (sqrtf(gram[triidx(v, v)]) + 1e-10f);

    float logit[VV];
#pragma unroll
    for (int j = 0; j < VV; ++j) logit[j] = sB[j];
    int k = 0;
#pragma unroll
    for (int v = 0; v < VV; ++v) {
#pragma unroll
      for (int w = 0; w < VV; ++w) {
        if (w == v) continue;
        int a = v < w ? v : w, b2 = v < w ? w : v;
        float s = gram[triidx(a, b2)] * inv[v] * inv[w];
#pragma unroll
        for (int j = 0; j < VV; ++j) logit[j] += s * sW[k * VV + j];
        ++k;
      }
    }

    float mx = logit[0];
#pragma unroll
    for (int j = 1; j < VV; ++j) mx = fmaxf(mx, logit[j]);
    float wt[VV], se = 0.f;
#pragma unroll
    for (int j = 0; j < VV; ++j) {
      wt[j] = __expf(logit[j] - mx);
      se += wt[j];
    }
    float rse = 1.f / se;
#pragma unroll
    for (int j = 0; j < VV; ++j) wt[j] = wt[j] * rse * mk[j];

#pragma unroll
    for (int c = 0; c < CPL; ++c) {
      float acc = 0.f;
#pragma unroll
      for (int v = 0; v < VV; ++v) acc += wt[v] * f[v][c];
      sFV[vloc * 25 + CPL * lr + c] = acc;
    }
    if (lr == 0) {
      sFV[vloc * 25 + CC] = zmean;
#pragma unroll
      for (int j = 0; j < VV; ++j) sVW[vloc * 9 + j] = wt[j];
      sCNT[vloc] = msum;
    }
  }
  __syncthreads();

  int vb = blockIdx.x * 64;
  int cv = min(64, n - vb);
  if (cv == 64) {
    float4* dfv = (float4*)(out + (size_t)vb * 25);
    for (int t = tid; t < 400; t += 256) dfv[t] = sFV4[t];
    float4* dvw = (float4*)(out + (size_t)n * 25 + (size_t)vb * 9);
    for (int t = tid; t < 144; t += 256) dvw[t] = sVW4[t];
    if (tid < 64) out[(size_t)n * 34 + vb + tid] = sCNT[tid];
  } else if (cv > 0) {
    for (int t = tid; t < cv * 25; t += 256) out[(size_t)vb * 25 + t] = sFV[t];
    for (int t = tid; t < cv * 9; t += 256) out[(size_t)n * 25 + (size_t)vb * 9 + t] = sVW[t];
    if (tid < cv) out[(size_t)n * 34 + vb + tid] = sCNT[tid];
  }
}

extern "C" void kernel_launch(void* const* d_in, const int* in_sizes, int n_in,
                              void* d_out, int out_size, void* d_ws, size_t ws_size,
                              hipStream_t stream) {
  const int* coords = (const int*)d_in[0];
  const float* feats = (const float*)d_in[1];
  const float* proj_feat = (const float*)d_in[2];
  const float* proj_img = (const float*)d_in[3];
  const float* origin = (const float*)d_in[4];
  const float* W_vs = (const float*)d_in[5];
  const float* b_vs = (const float*)d_in[6];
  const float* voxel_size = (const float*)d_in[7];
  const int* scale = (const int*)d_in[8];
  const int* im_h = (const int*)d_in[9];
  const int* im_w = (const int*)d_in[10];

  int n = in_sizes[0] / 4;
  int nbq = (n + 63) / 64;          // main blocks (64 voxels each)
  int nbz = (n + 255) / 256;        // per-voxel grids
  int nbt = (VV * HW + 255) / 256;  // transpose blocks
  int nbp = nbq > nbz ? nbq : nbz;  // partials sizing

  // workspace layout
  size_t off = 0;
  float* musd = (float*)d_ws;                      off += 256;
  int* hist = (int*)((char*)d_ws + off);           off += NBKT_PAD * 4;
  int* offs = (int*)((char*)d_ws + off);           off += NBKT_PAD * 4;
  int* cnt  = (int*)((char*)d_ws + off);           off += NBKT_PAD * 4;
  float* wsym = (float*)((char*)d_ws + off);       off += NOFF * VV * 4;
  off = (off + 255) & ~(size_t)255;
  double* partials = (double*)((char*)d_ws + off); off += (size_t)nbp * 3 * 8;
  off = (off + 255) & ~(size_t)255;
  int2* cvox2 = (int2*)((char*)d_ws + off);        size_t cvox_off = off; off += (size_t)n * 8;
  off = (off + 255) & ~(size_t)255;
  uint4* tf16 = (uint4*)((char*)d_ws + off);
  size_t tf16_bytes = (size_t)VV * HW * 64;   // padded 64B texels
  size_t need_full = off + tf16_bytes;
  size_t tf32_bytes = (size_t)VV * HW * CC * 4;

  if (ws_size >= need_full) {
    // ---- tier A: 5 dispatches ----
    // zero hist only (cnt zeroed by k_scan; d_ws is poisoned 0xAA — R3 lesson)
    (void)hipMemsetAsync(hist, 0, (size_t)NBKT_PAD * 4, stream);
    k_t16_hist<<<dim3(nbt + nbz), dim3(256), 0, stream>>>(feats, tf16, coords, hist, n, nbt);
    k_scan<<<dim3(1), dim3(256), 0, stream>>>(hist, offs, cnt, W_vs, wsym);
    k_scatter_zm<<<dim3(nbz), dim3(256), 0, stream>>>(
        coords, offs, cnt, cvox2, proj_feat, proj_img, origin, voxel_size,
        scale, im_h, im_w, partials, n);
    vf_main4p<<<dim3(nbq), dim3(256), 0, stream>>>(
        cvox2, tf16, proj_feat, origin, wsym, b_vs, voxel_size, scale,
        partials, nbz, (float*)d_out, n);
  } else if (ws_size >= cvox_off + tf32_bytes) {
    // ---- tier B: no permutation, fp32 map ----
    float* tfb = (float*)((char*)d_ws + cvox_off);
    vf_transpose<<<dim3(nbt), dim3(256), 0, stream>>>(feats, tfb, VV * HW);
    vf_main4<<<dim3(nbq), dim3(256), 0, stream>>>(
        coords, tfb, proj_feat, proj_img, origin, W_vs, b_vs, voxel_size,
        scale, im_h, im_w, (float*)d_out, n);
    k_zpart<<<dim3(nbz), dim3(256), 0, stream>>>((const float*)d_out, partials, n);
    vf_reduce<<<dim3(1), dim3(256), 0, stream>>>(partials, nbz, musd);
    vf_znorm<<<dim3(nbz), dim3(256), 0, stream>>>((float*)d_out, musd, n);
  }
}